// Round 12
// baseline (351.220 us; speedup 1.0000x reference)
//
#include <hip/hip_runtime.h>
#include <hip/hip_bf16.h>
#include <cstdint>
#include <cstddef>

typedef unsigned short u16;
typedef __bf16 bf16x8 __attribute__((ext_vector_type(8)));
typedef float f32x4 __attribute__((ext_vector_type(4)));

#define MFMA_BF16(a, b, c) __builtin_amdgcn_mfma_f32_16x16x32_bf16((a), (b), (c), 0, 0, 0)

// global -> LDS async copy, 16B per lane. LDS layout must be wave-uniform base + lane*16.
#define GLDS16(g, l)                                                        \
  __builtin_amdgcn_global_load_lds(                                         \
      (__attribute__((address_space(1))) void*)(void*)(g),                  \
      (__attribute__((address_space(3))) void*)(void*)(l), 16, 0, 0)

// scale folded into q at QKV epilogue: 1/sqrt(64) * log2(e), so softmax uses exp2 directly
#define QSCALE 0.18033688011112042f
#define PSTRIDE ((size_t)4096 * 768)

__device__ __forceinline__ u16 f2bf(float x) {
  union { float f; unsigned u; } c; c.f = x;
  unsigned u = c.u;
  unsigned r = (u + 0x7fffu + ((u >> 16) & 1u)) >> 16;  // RNE
  return (u16)r;
}
__device__ __forceinline__ float bf2f(u16 x) {
  union { unsigned u; float f; } c; c.u = (unsigned)x << 16; return c.f;
}

// ---------------- fused prep kernel: 6 transposes + bias concat + x convert ----------
__global__ __launch_bounds__(256) void prep_weights_k(
    const float* __restrict__ Wq, const float* __restrict__ Wk,
    const float* __restrict__ Wv, const float* __restrict__ Wo,
    const float* __restrict__ W1, const float* __restrict__ W2,
    const float* __restrict__ bq, const float* __restrict__ bk,
    const float* __restrict__ bv, const float* __restrict__ x,
    u16* __restrict__ WqkvT, u16* __restrict__ WoT,
    u16* __restrict__ W1T, u16* __restrict__ W2T, float* __restrict__ bqkv,
    u16* __restrict__ xb) {
  const int id = blockIdx.x;
  if (id >= 6921) {  // x convert, 4 elems/thread
    const int i = ((id - 6921) * 256 + threadIdx.x) * 4;
    const float4 v = *(const float4*)(x + i);
    ushort4 o;
    o.x = f2bf(v.x); o.y = f2bf(v.y); o.z = f2bf(v.z); o.w = f2bf(v.w);
    *(ushort4*)(xb + i) = o;
    return;
  }
  if (id >= 6912) {  // bias concat
    int i = (id - 6912) * 256 + threadIdx.x;
    if (i < 768) bqkv[i] = bq[i];
    else if (i < 1536) bqkv[i] = bk[i - 768];
    else if (i < 2304) bqkv[i] = bv[i - 1536];
    return;
  }
  const float* in; u16* out; int K, N, bx, by;
  if (id < 2304) {
    const int mat = id / 576, t = id - mat * 576;
    in = (mat == 0) ? Wq : (mat == 1) ? Wk : (mat == 2) ? Wv : Wo;
    out = (mat == 0) ? WqkvT : (mat == 1) ? WqkvT + 768 * 768
        : (mat == 2) ? WqkvT + 2 * 768 * 768 : WoT;
    K = 768; N = 768; bx = (t % 24) * 32; by = (t / 24) * 32;
  } else if (id < 4608) {
    const int t = id - 2304;
    in = W1; out = W1T; K = 768; N = 3072;
    bx = (t % 96) * 32; by = (t / 96) * 32;
  } else {
    const int t = id - 4608;
    in = W2; out = W2T; K = 3072; N = 768;
    bx = (t % 24) * 32; by = (t / 24) * 32;
  }
  __shared__ float tile[32][33];
  const int tx = threadIdx.x & 31, ty = threadIdx.x >> 5;
#pragma unroll
  for (int j = 0; j < 32; j += 8)
    tile[ty + j][tx] = in[(size_t)(by + ty + j) * N + bx + tx];
  __syncthreads();
#pragma unroll
  for (int j = 0; j < 32; j += 8)
    out[(size_t)(bx + ty + j) * K + by + tx] = f2bf(tile[tx][ty + j]);
}

// ---------------- GEMM: wave-private 64x64 tile, BK=32, NO BARRIERS ----------------
// One wave (64 threads) per block; each wave owns a 64x64 C-tile and stages its
// own A/B tiles into private LDS (16 KB: 2 bufs x (4KB A + 4KB B)). With no
// cross-wave sharing there is NO __syncthreads -> no vmcnt(0)+barrier drain.
// Pipeline: [ds_read frags of buf t] [sched_barrier] [prefetch t+1] [MFMAs].
// The compiler's alias-conservative vmcnt before the ds_reads waits only on
// stage(t) (issued one compute-phase earlier) because stage(t+1) is issued
// AFTER the reads -> fine-grained wait, AITER-style, at source level.
// LDS line-pair swizzle (proven 0-conflict in R9): 2 rows (64 B) = one 128-B
// line of 8 16-B slots; logical p=(row&1)*4+chunk stored at slot p^(line&7).
// EPI: 0 = QKV scatter   2 = gelu->bf16   3 = bf16 split-K partial
template <int EPI>
__device__ __forceinline__ void gemm_wave_body(
    u16* lsA, u16* lsB,
    const u16* __restrict__ A, const u16* __restrict__ BT,
    const float* __restrict__ bias, int M, int N, int K, int kchunk,
    u16* __restrict__ outb,
    u16* __restrict__ qo, u16* __restrict__ ko, u16* __restrict__ vto) {
  const int lane = threadIdx.x;
  const int lrow = lane & 15, quad = lane >> 4;
  const int m0 = blockIdx.y * 64, n0 = blockIdx.x * 64;
  const int kbeg = blockIdx.z * kchunk;

  f32x4 acc[4][4];
#pragma unroll
  for (int i = 0; i < 4; ++i)
#pragma unroll
    for (int j = 0; j < 4; ++j) acc[i][j] = (f32x4){0.f, 0.f, 0.f, 0.f};

  // staging map: instr i covers lines i*8..i*8+7; lane -> (line, slot)
  const int g = lane >> 3;            // line within 8-line group
  const int p = (lane & 7) ^ g;       // logical pos = (row&1)*4 + chunk
  const int rpar = p >> 2;            // row parity within line
  const int scol = (p & 3) * 8;       // u16 col within BK=32

  auto stage = [&](int k0, int buf) {
    char* da = (char*)(lsA + buf * 2048);
    char* db = (char*)(lsB + buf * 2048);
#pragma unroll
    for (int i = 0; i < 4; ++i) {
      const int row = (i * 8 + g) * 2 + rpar;
      GLDS16(A + (size_t)(m0 + row) * K + k0 + scol, da + i * 1024 + lane * 16);
      GLDS16(BT + (size_t)(n0 + row) * K + k0 + scol, db + i * 1024 + lane * 16);
    }
  };

  // fragment read map (R9-proven conflict-free)
  const int lline = lrow >> 1;
  const int lslot = (((lrow & 1) << 2) + quad) ^ lline;
  const int rdoff = lslot * 8;

  const int niter = kchunk >> 5;
  stage(kbeg, 0);
  for (int t = 0; t < niter; ++t) {
    const u16* Ab = lsA + (t & 1) * 2048;
    const u16* Bb = lsB + (t & 1) * 2048;
    bf16x8 af[4], bfr[4];
#pragma unroll
    for (int ms = 0; ms < 4; ++ms)
      af[ms] = *(const bf16x8*)&Ab[(ms * 8 + lline) * 64 + rdoff];
#pragma unroll
    for (int ns = 0; ns < 4; ++ns)
      bfr[ns] = *(const bf16x8*)&Bb[(ns * 8 + lline) * 64 + rdoff];
    __builtin_amdgcn_sched_barrier(0);  // keep prefetch AFTER the frag reads
    if (t + 1 < niter) stage(kbeg + (t + 1) * 32, (t + 1) & 1);
#pragma unroll
    for (int ms = 0; ms < 4; ++ms)
#pragma unroll
      for (int ns = 0; ns < 4; ++ns)
        acc[ms][ns] = MFMA_BF16(af[ms], bfr[ns], acc[ms][ns]);
  }

  u16* const pb = (EPI == 3) ? outb + (size_t)blockIdx.z * PSTRIDE : outb;
#pragma unroll
  for (int ms = 0; ms < 4; ++ms) {
    const int rbase = m0 + ms * 16 + quad * 4;
#pragma unroll
    for (int ns = 0; ns < 4; ++ns) {
      const int col = n0 + ns * 16 + lrow;
      if constexpr (EPI == 3) {
#pragma unroll
        for (int r = 0; r < 4; ++r)
          pb[(size_t)(rbase + r) * N + col] = f2bf(acc[ms][ns][r]);
      } else if constexpr (EPI == 2) {
        const float bcol = bias[col];
#pragma unroll
        for (int r = 0; r < 4; ++r) {
          float v = acc[ms][ns][r] + bcol;
          float gg = 0.5f * v * (1.0f + erff(v * 0.7071067811865476f));
          outb[(size_t)(rbase + r) * N + col] = f2bf(gg);
        }
      } else {  // QKV scatter
        const float bcol = bias[col];
        const int which = col / 768;
        const int rem = col - which * 768;
        const int hh = rem >> 6, dd = rem & 63;
        const int bI = rbase >> 11, sI = rbase & 2047;
        const size_t bh = (size_t)bI * 12 + hh;
        if (which == 0) {
#pragma unroll
          for (int r = 0; r < 4; ++r)
            qo[(bh * 2048 + sI + r) * 64 + dd] = f2bf((acc[ms][ns][r] + bcol) * QSCALE);
        } else if (which == 1) {
#pragma unroll
          for (int r = 0; r < 4; ++r)
            ko[(bh * 2048 + sI + r) * 64 + dd] = f2bf(acc[ms][ns][r] + bcol);
        } else {
          ushort4 pk;
          pk.x = f2bf(acc[ms][ns][0] + bcol);
          pk.y = f2bf(acc[ms][ns][1] + bcol);
          pk.z = f2bf(acc[ms][ns][2] + bcol);
          pk.w = f2bf(acc[ms][ns][3] + bcol);
          *(ushort4*)(vto + (bh * 64 + dd) * 2048 + sI) = pk;
        }
      }
    }
  }
}

#define GEMM_WRAP(name, EPI)                                                   \
  __global__ __launch_bounds__(64) void name(                                  \
      const u16* __restrict__ A, const u16* __restrict__ BT,                   \
      const float* __restrict__ bias, int M, int N, int K, int kchunk,         \
      u16* __restrict__ outb, u16* __restrict__ qo, u16* __restrict__ ko,      \
      u16* __restrict__ vto) {                                                 \
    __shared__ __align__(16) u16 lsA[2 * 64 * 32];                             \
    __shared__ __align__(16) u16 lsB[2 * 64 * 32];                             \
    gemm_wave_body<EPI>(lsA, lsB, A, BT, bias, M, N, K, kchunk, outb, qo, ko,  \
                        vto);                                                  \
  }
GEMM_WRAP(gemm_qkv_k, 0)
GEMM_WRAP(gemm_ffn1_k, 2)
GEMM_WRAP(gemm_wo_k, 3)
GEMM_WRAP(gemm_ffn2_k, 3)
#undef GEMM_WRAP

// ---------------- flash attention (Q=128/block, split-KV, dbuf K/V) ----------------
// [R5-proven: ~46 us, 0 bank conflicts. S^T variant regressed - do not reapply.]
__global__ __launch_bounds__(256) void attn_kernel(
    const u16* __restrict__ q, const u16* __restrict__ k,
    const u16* __restrict__ vT, u16* __restrict__ opart,
    float* __restrict__ lpart) {
  __shared__ __align__(16) u16 lsK[2 * 64 * 64];  // [buf][s][d], swizzled
  __shared__ __align__(16) u16 lsV[2 * 64 * 64];  // [buf][d][s], swizzled
  __shared__ __align__(16) u16 lsP[4][32 * 64];   // per-wave [m 0..31][j], swizzled
  const int tid = threadIdx.x;
  const int w = tid >> 6, lane = tid & 63;
  const int lrow = lane & 15, quad = lane >> 4;
  const int bh = blockIdx.y;
  const int b = bh / 12, h = bh - b * 12;
  const int q0 = blockIdx.x * 128;
  const int z = blockIdx.z;
  const int kvbeg = z * 1024;

  const u16* qbase = q + (size_t)bh * 2048 * 64;
  const u16* kbase = k + (size_t)bh * 2048 * 64;
  const u16* vbase = vT + (size_t)bh * 64 * 2048;

  bf16x8 qf[2][2];
#pragma unroll
  for (int m = 0; m < 2; ++m) {
    const int qrow = q0 + w * 32 + m * 16 + lrow;
    qf[m][0] = *(const bf16x8*)(qbase + (size_t)qrow * 64 + quad * 8);
    qf[m][1] = *(const bf16x8*)(qbase + (size_t)qrow * 64 + 32 + quad * 8);
  }

  float lsum[2][4] = {{0.f, 0.f, 0.f, 0.f}, {0.f, 0.f, 0.f, 0.f}};
  f32x4 oacc[2][4];
#pragma unroll
  for (int m = 0; m < 2; ++m)
#pragma unroll
    for (int d = 0; d < 4; ++d) oacc[m][d] = (f32x4){0.f, 0.f, 0.f, 0.f};

  const int off = tid * 16;
  const int srow = off >> 7;
  const int schunk = (off >> 4) & 7;
  const int sxc = schunk ^ (srow & 7);
  const int ksrc = srow * 64 + sxc * 8;
  const int vsrc0 = srow * 2048 + sxc * 8;

  const int c0 = quad ^ (lrow & 7);
  const int rd0 = c0 * 8, rd1 = (c0 ^ 4) * 8;

  u16* const lsPw = &lsP[w][0];
  const int jhi_base = lrow >> 3, jlo = lrow & 7;

  auto stage = [&](int kt, int buf) {
    char* dk = (char*)(lsK + buf * 4096);
    char* dv = (char*)(lsV + buf * 4096);
    GLDS16(kbase + (size_t)kt * 64 + ksrc, dk + off);
    GLDS16(kbase + (size_t)(kt + 32) * 64 + ksrc, dk + 4096 + off);
    GLDS16(vbase + vsrc0 + kt, dv + off);
    GLDS16(vbase + vsrc0 + kt + 32 * 2048, dv + 4096 + off);
  };

  stage(kvbeg, 0);
  for (int t = 0; t < 16; ++t) {
    __syncthreads();
    if (t < 15) stage(kvbeg + (t + 1) * 64, (t + 1) & 1);
    const u16* Kb = lsK + (t & 1) * 4096;
    const u16* Vb = lsV + (t & 1) * 4096;

    f32x4 sc[2][4];
#pragma unroll
    for (int ns = 0; ns < 4; ++ns) {
      const u16* kr = Kb + (ns * 16 + lrow) * 64;
      bf16x8 kf0 = *(const bf16x8*)(kr + rd0);
      bf16x8 kf1 = *(const bf16x8*)(kr + rd1);
#pragma unroll
      for (int m = 0; m < 2; ++m) {
        sc[m][ns] = (f32x4){0.f, 0.f, 0.f, 0.f};
        sc[m][ns] = MFMA_BF16(qf[m][0], kf0, sc[m][ns]);
        sc[m][ns] = MFMA_BF16(qf[m][1], kf1, sc[m][ns]);
      }
    }

#pragma unroll
    for (int m = 0; m < 2; ++m)
#pragma unroll
      for (int ns = 0; ns < 4; ++ns) {
        const int jhi = ns * 2 + jhi_base;
#pragma unroll
        for (int r = 0; r < 4; ++r) {
          float p = __builtin_amdgcn_exp2f(sc[m][ns][r]);
          lsum[m][r] += p;
          union { float f; unsigned u; } cv; cv.f = p;
          const int row7 = (quad * 4 + r) & 7;
          lsPw[(m * 16 + quad * 4 + r) * 64 + ((jhi ^ row7) * 8) + jlo] =
              (u16)(cv.u >> 16);
        }
      }

    // PV (wave-private P: same-wave DS ordering, no barrier needed)
#pragma unroll
    for (int d = 0; d < 4; ++d) {
      const u16* vr = Vb + (d * 16 + lrow) * 64;
      bf16x8 vf0 = *(const bf16x8*)(vr + rd0);
      bf16x8 vf1 = *(const bf16x8*)(vr + rd1);
#pragma unroll
      for (int m = 0; m < 2; ++m) {
        const u16* pr = lsPw + (m * 16 + lrow) * 64;
        bf16x8 pf0 = *(const bf16x8*)(pr + rd0);
        bf16x8 pf1 = *(const bf16x8*)(pr + rd1);
        oacc[m][d] = MFMA_BF16(pf0, vf0, oacc[m][d]);
        oacc[m][d] = MFMA_BF16(pf1, vf1, oacc[m][d]);
      }
    }
  }

#pragma unroll
  for (int m = 0; m < 2; ++m)
#pragma unroll
    for (int r = 0; r < 4; ++r) {
#pragma unroll
      for (int mm = 1; mm <= 8; mm <<= 1)
        lsum[m][r] += __shfl_xor(lsum[m][r], mm);
    }

  u16* const op = opart + (size_t)z * PSTRIDE;
#pragma unroll
  for (int m = 0; m < 2; ++m) {
    const int srow_out = q0 + w * 32 + m * 16 + quad * 4;
#pragma unroll
    for (int d = 0; d < 4; ++d)
#pragma unroll
      for (int r = 0; r < 4; ++r)
        op[(size_t)(b * 2048 + srow_out + r) * 768 + h * 64 + d * 16 + lrow] =
            f2bf(oacc[m][d][r]);
    if (lrow == 0) {
#pragma unroll
      for (int r = 0; r < 4; ++r)
        lpart[(size_t)(z * 24 + bh) * 2048 + srow_out + r] = lsum[m][r];
    }
  }
}

// ctx = (o0 + o1) / (l0 + l1), bf16; vectorized x4
__global__ __launch_bounds__(256) void attn_combine_k(
    const u16* __restrict__ op, const float* __restrict__ lp,
    u16* __restrict__ ctx) {
  const unsigned idx = (blockIdx.x * 256u + threadIdx.x) * 4u;
  const unsigned row = idx / 768u;
  const unsigned c = idx - row * 768u;
  const int b = row >> 11, s = row & 2047;
  const int h = c >> 6;
  const size_t li = (size_t)(b * 12 + h) * 2048 + s;
  const float rinv = 1.f / (lp[li] + lp[(size_t)24 * 2048 + li]);
  ushort4 o0 = *(const ushort4*)(op + idx);
  ushort4 o1 = *(const ushort4*)(op + PSTRIDE + idx);
  ushort4 out;
#define CMB(fld) out.fld = f2bf((bf2f(o0.fld) + bf2f(o1.fld)) * rinv);
  CMB(x) CMB(y) CMB(z) CMB(w)
#undef CMB
  *(ushort4*)(ctx + idx) = out;
}

// ---------------- bf16-partial-sum + bias + residual + layernorm ----------------
__global__ __launch_bounds__(256) void ln_kernel(
    const u16* __restrict__ parts, int nparts, const float* __restrict__ bias,
    const float* __restrict__ res, const float* __restrict__ g,
    const float* __restrict__ bb, float* __restrict__ outf, u16* __restrict__ outb) {
  const int row = blockIdx.x;
  const int tid = threadIdx.x;
  const float* pr = res + (size_t)row * 768;
  float v[3], s = 0.f, s2 = 0.f;
#pragma unroll
  for (int j = 0; j < 3; ++j) {
    const int c = tid + j * 256;
    float t = bias[c] + pr[c];
    for (int p = 0; p < nparts; ++p)
      t += bf2f(parts[p * PSTRIDE + (size_t)row * 768 + c]);
    v[j] = t; s += t; s2 += t * t;
  }
#pragma unroll
  for (int m = 32; m > 0; m >>= 1) {
    s += __shfl_xor(s, m);
    s2 += __shfl_xor(s2, m);
  }
  __shared__ float red[8];
  const int w = tid >> 6, lane = tid & 63;
  if (lane == 0) { red[w] = s; red[4 + w] = s2; }
  __syncthreads();
  s = red[0] + red[1] + red[2] + red[3];
  s2 = red[4] + red[5] + red[6] + red[7];
  const float mu = s * (1.f / 768.f);
  const float var = s2 * (1.f / 768.f) - mu * mu;
  const float rstd = rsqrtf(var + 1e-5f);
#pragma unroll
  for (int j = 0; j < 3; ++j) {
    const int c = tid + j * 256;
    const float y = (v[j] - mu) * rstd * g[c] + bb[c];
    if (outf) outf[(size_t)row * 768 + c] = y;
    if (outb) outb[(size_t)row * 768 + c] = f2bf(y);
  }
}

// ---------------- launch ----------------
extern "C" void kernel_launch(void* const* d_in, const int* in_sizes, int n_in,
                              void* d_out, int out_size, void* d_ws, size_t ws_size,
                              hipStream_t stream) {
  const float* x    = (const float*)d_in[0];
  const float* Wq   = (const float*)d_in[1];
  const float* bq   = (const float*)d_in[2];
  const float* Wk   = (const float*)d_in[3];
  const float* bk   = (const float*)d_in[4];
  const float* Wv   = (const float*)d_in[5];
  const float* bv   = (const float*)d_in[6];
  const float* Wo   = (const float*)d_in[7];
  const float* bo   = (const float*)d_in[8];
  const float* W1   = (const float*)d_in[9];
  const float* b1   = (const float*)d_in[10];
  const float* W2   = (const float*)d_in[11];
  const float* b2   = (const float*)d_in[12];
  const float* ln1g = (const float*)d_in[13];
  const float* ln1b = (const float*)d_in[14];
  const float* ln2g = (const float*)d_in[15];
  const float* ln2b = (const float*)d_in[16];

  char* ws = (char*)d_ws;
  size_t off = 0;
  auto alloc = [&](size_t bytes) {
    void* p = ws + off;
    off += (bytes + 255) & ~(size_t)255;
    return p;
  };
  // persistent weights
  u16*  WqkvT = (u16*)alloc(2304ull * 768 * 2);
  u16*  WoT   = (u16*)alloc(768ull * 768 * 2);
  u16*  W1T   = (u16*)alloc(3072ull * 768 * 2);
  u16*  W2T   = (u16*)alloc(768ull * 3072 * 2);
  float* bqkv = (float*)alloc(2304 * 4);
  // big aliased region: [xb qb kb vtb] (25.2 MB); FFN2 bf16 partials overlay it.
  char* bigbase = (char*)alloc(0);
  u16*  xb    = (u16*)alloc(4096ull * 768 * 2);
  u16*  qb    = (u16*)alloc(24ull * 2048 * 64 * 2);
  u16*  kb    = (u16*)alloc(24ull * 2048 * 64 * 2);
  u16*  vtb   = (u16*)alloc(24ull * 64 * 2048 * 2);
  u16*  ctx   = (u16*)alloc(4096ull * 768 * 2);
  // Wo bf16 partials (z=2); attn opart aliases this region (dead by Wo time)
  u16*  wop   = (u16*)alloc(2ull * PSTRIDE * 2);
  u16*  opart = wop;
  float* lpart = (float*)alloc(2ull * 24 * 2048 * 4);
  u16*  f2bp  = (u16*)bigbase;   // FFN2 partials (z=4), aliased
  // tail
  float* hbuf  = (float*)alloc(4096ull * 768 * 4);
  u16*  hb    = (u16*)alloc(4096ull * 768 * 2);
  u16*  f1    = (u16*)alloc(4096ull * 3072 * 2);

  // one fused prep launch: 6 transposes + bias concat + x convert
  prep_weights_k<<<9993, 256, 0, stream>>>(Wq, Wk, Wv, Wo, W1, W2, bq, bk, bv, x,
                                           WqkvT, WoT, W1T, W2T, bqkv, xb);

  // QKV: M=4096 N=2304 K=768 (wave tiles 64x64)
  gemm_qkv_k<<<dim3(36, 64, 1), 64, 0, stream>>>(xb, WqkvT, bqkv, 4096, 2304, 768, 768,
                                                 nullptr, qb, kb, vtb);
  // attention: Q=128/block, split-KV z=2
  attn_kernel<<<dim3(16, 24, 2), 256, 0, stream>>>(qb, kb, vtb, opart, lpart);
  attn_combine_k<<<3072, 256, 0, stream>>>(opart, lpart, ctx);
  // Wo: split-K z=2 -> 2 bf16 partials in wop (overwrites dead opart)
  gemm_wo_k<<<dim3(12, 64, 2), 64, 0, stream>>>(ctx, WoT, nullptr, 4096, 768, 768, 384,
                                                wop, nullptr, nullptr, nullptr);
  ln_kernel<<<4096, 256, 0, stream>>>(wop, 2, bo, x, ln1g, ln1b, hbuf, hb);
  // FFN1: M=4096 N=3072 K=768, GELU epilogue
  gemm_ffn1_k<<<dim3(48, 64, 1), 64, 0, stream>>>(hb, W1T, b1, 4096, 3072, 768, 768,
                                                  f1, nullptr, nullptr, nullptr);
  // FFN2: split-K z=4 -> 4 bf16 partials in f2bp (aliased over dead buffers)
  gemm_ffn2_k<<<dim3(12, 64, 4), 64, 0, stream>>>(f1, W2T, nullptr, 4096, 768, 3072, 768,
                                                  f2bp, nullptr, nullptr, nullptr);
  ln_kernel<<<4096, 256, 0, stream>>>(f2bp, 4, b2, hbuf, ln2g, ln2b, (float*)d_out, nullptr);
}

// Round 14
// 301.175 us; speedup vs baseline: 1.1662x; 1.1662x over previous
//
#include <hip/hip_runtime.h>
#include <hip/hip_bf16.h>
#include <cstdint>
#include <cstddef>

typedef unsigned short u16;
typedef __bf16 bf16x8 __attribute__((ext_vector_type(8)));
typedef float f32x4 __attribute__((ext_vector_type(4)));

#define MFMA_BF16(a, b, c) __builtin_amdgcn_mfma_f32_16x16x32_bf16((a), (b), (c), 0, 0, 0)

// global -> LDS async copy, 16B per lane. LDS layout must be wave-uniform base + lane*16.
#define GLDS16(g, l)                                                        \
  __builtin_amdgcn_global_load_lds(                                         \
      (__attribute__((address_space(1))) void*)(void*)(g),                  \
      (__attribute__((address_space(3))) void*)(void*)(l), 16, 0, 0)

// scale folded into q at QKV epilogue: 1/sqrt(64) * log2(e), so softmax uses exp2 directly
#define QSCALE 0.18033688011112042f
#define PSTRIDE ((size_t)4096 * 768)
#define KVSPLIT 4

__device__ __forceinline__ u16 f2bf(float x) {
  union { float f; unsigned u; } c; c.f = x;
  unsigned u = c.u;
  unsigned r = (u + 0x7fffu + ((u >> 16) & 1u)) >> 16;  // RNE
  return (u16)r;
}
__device__ __forceinline__ float bf2f(u16 x) {
  union { unsigned u; float f; } c; c.u = (unsigned)x << 16; return c.f;
}

// ---------------- fused prep kernel: 6 transposes + bias concat + x convert ----------
__global__ __launch_bounds__(256) void prep_weights_k(
    const float* __restrict__ Wq, const float* __restrict__ Wk,
    const float* __restrict__ Wv, const float* __restrict__ Wo,
    const float* __restrict__ W1, const float* __restrict__ W2,
    const float* __restrict__ bq, const float* __restrict__ bk,
    const float* __restrict__ bv, const float* __restrict__ x,
    u16* __restrict__ WqkvT, u16* __restrict__ WoT,
    u16* __restrict__ W1T, u16* __restrict__ W2T, float* __restrict__ bqkv,
    u16* __restrict__ xb) {
  const int id = blockIdx.x;
  if (id >= 6921) {  // x convert, 4 elems/thread
    const int i = ((id - 6921) * 256 + threadIdx.x) * 4;
    const float4 v = *(const float4*)(x + i);
    ushort4 o;
    o.x = f2bf(v.x); o.y = f2bf(v.y); o.z = f2bf(v.z); o.w = f2bf(v.w);
    *(ushort4*)(xb + i) = o;
    return;
  }
  if (id >= 6912) {  // bias concat
    int i = (id - 6912) * 256 + threadIdx.x;
    if (i < 768) bqkv[i] = bq[i];
    else if (i < 1536) bqkv[i] = bk[i - 768];
    else if (i < 2304) bqkv[i] = bv[i - 1536];
    return;
  }
  const float* in; u16* out; int K, N, bx, by;
  if (id < 2304) {
    const int mat = id / 576, t = id - mat * 576;
    in = (mat == 0) ? Wq : (mat == 1) ? Wk : (mat == 2) ? Wv : Wo;
    out = (mat == 0) ? WqkvT : (mat == 1) ? WqkvT + 768 * 768
        : (mat == 2) ? WqkvT + 2 * 768 * 768 : WoT;
    K = 768; N = 768; bx = (t % 24) * 32; by = (t / 24) * 32;
  } else if (id < 4608) {
    const int t = id - 2304;
    in = W1; out = W1T; K = 768; N = 3072;
    bx = (t % 96) * 32; by = (t / 96) * 32;
  } else {
    const int t = id - 4608;
    in = W2; out = W2T; K = 3072; N = 768;
    bx = (t % 24) * 32; by = (t / 24) * 32;
  }
  __shared__ float tile[32][33];
  const int tx = threadIdx.x & 31, ty = threadIdx.x >> 5;
#pragma unroll
  for (int j = 0; j < 32; j += 8)
    tile[ty + j][tx] = in[(size_t)(by + ty + j) * N + bx + tx];
  __syncthreads();
#pragma unroll
  for (int j = 0; j < 32; j += 8)
    out[(size_t)(bx + ty + j) * K + by + tx] = f2bf(tile[tx][ty + j]);
}

// ---------------- GEMM: C = A[MxK] @ B^T[NxK]^T (+ bias) ----------------
// [LOCKED: R9/R11-proven best by GRAPH total. BK=32 dbuf, one barrier/iter,
//  32 KB LDS, line-pair swizzle (0 conflicts).]
// 128x128 tile, 4 waves (2x2), wave = 64x64 = 4x4 mfma 16x16x32 subtiles.
// EPI: 0 = QKV scatter   2 = gelu->bf16   3 = BF16 split-K partial
template <int EPI>
__global__ __launch_bounds__(256) void gemm_bt(
    const u16* __restrict__ A, const u16* __restrict__ BT,
    const float* __restrict__ bias, int M, int N, int K, int kchunk,
    float* __restrict__ outf, u16* __restrict__ outb,
    u16* __restrict__ qo, u16* __restrict__ ko, u16* __restrict__ vto) {
  __shared__ __align__(16) u16 lsA[2 * 128 * 32];
  __shared__ __align__(16) u16 lsB[2 * 128 * 32];
  const int tid = threadIdx.x;
  const int w = tid >> 6, lane = tid & 63;
  const int wm = w & 1, wn = w >> 1;
  const int lrow = lane & 15, quad = lane >> 4;
  const int m0 = blockIdx.y * 128, n0 = blockIdx.x * 128;
  const int kbeg = blockIdx.z * kchunk;

  f32x4 acc[4][4];
#pragma unroll
  for (int i = 0; i < 4; ++i)
#pragma unroll
    for (int j = 0; j < 4; ++j) acc[i][j] = (f32x4){0.f, 0.f, 0.f, 0.f};

  // staging: thread covers 16 B at LDS byte tid*16 of each 4 KB half-tile
  const int off = tid * 16;
  const int line = tid >> 3;           // 128-B line (2 rows of 64 B)
  const int slotp = tid & 7;           // 16-B slot within line
  const int p = slotp ^ (line & 7);    // logical pos = (row&1)*4 + chunk
  const int srow = line * 2 + (p >> 2);
  const int scol = (p & 3) * 8;        // u16 col within BK=32

  const u16* ga0 = A + (size_t)(m0 + srow) * K + scol;
  const u16* gb0 = BT + (size_t)(n0 + srow) * K + scol;

  auto stage = [&](int k0, int buf) {
    char* da = (char*)(lsA + buf * 4096);
    char* db = (char*)(lsB + buf * 4096);
    GLDS16(ga0 + k0, da + off);
    GLDS16(ga0 + k0 + (size_t)64 * K, da + 4096 + off);
    GLDS16(gb0 + k0, db + off);
    GLDS16(gb0 + k0 + (size_t)64 * K, db + 4096 + off);
  };

  // fragment read: row = wbase + ms*16 + lrow, chunk = quad
  const int lline = lrow >> 1;
  const int lslot = (((lrow & 1) << 2) + quad) ^ ((lrow >> 1) & 7);
  const int rdoff = lslot * 8;

  const int niter = kchunk >> 5;
  stage(kbeg, 0);
  for (int t = 0; t < niter; ++t) {
    __syncthreads();  // drains buf[t] prefetch (covered by compute of t-1)
    if (t + 1 < niter) stage(kbeg + (t + 1) * 32, (t + 1) & 1);
    const u16* Ab = lsA + (t & 1) * 4096;
    const u16* Bb = lsB + (t & 1) * 4096;
    bf16x8 af[4], bfr[4];
#pragma unroll
    for (int ms = 0; ms < 4; ++ms)
      af[ms] = *(const bf16x8*)&Ab[(wm * 32 + ms * 8 + lline) * 64 + rdoff];
#pragma unroll
    for (int ns = 0; ns < 4; ++ns)
      bfr[ns] = *(const bf16x8*)&Bb[(wn * 32 + ns * 8 + lline) * 64 + rdoff];
#pragma unroll
    for (int ms = 0; ms < 4; ++ms)
#pragma unroll
      for (int ns = 0; ns < 4; ++ns)
        acc[ms][ns] = MFMA_BF16(af[ms], bfr[ns], acc[ms][ns]);
  }

  u16* const pb = (EPI == 3) ? outb + (size_t)blockIdx.z * PSTRIDE : outb;
#pragma unroll
  for (int ms = 0; ms < 4; ++ms) {
    const int rbase = m0 + wm * 64 + ms * 16 + quad * 4;
#pragma unroll
    for (int ns = 0; ns < 4; ++ns) {
      const int col = n0 + wn * 64 + ns * 16 + lrow;
      if constexpr (EPI == 3) {
#pragma unroll
        for (int r = 0; r < 4; ++r)
          pb[(size_t)(rbase + r) * N + col] = f2bf(acc[ms][ns][r]);
      } else if constexpr (EPI == 2) {
        const float bcol = bias[col];
#pragma unroll
        for (int r = 0; r < 4; ++r) {
          float v = acc[ms][ns][r] + bcol;
          float g = 0.5f * v * (1.0f + erff(v * 0.7071067811865476f));
          outb[(size_t)(rbase + r) * N + col] = f2bf(g);
        }
      } else {  // QKV scatter
        const float bcol = bias[col];
        const int which = col / 768;
        const int rem = col - which * 768;
        const int hh = rem >> 6, dd = rem & 63;
        const int bI = rbase >> 11, sI = rbase & 2047;
        const size_t bh = (size_t)bI * 12 + hh;
        if (which == 0) {
#pragma unroll
          for (int r = 0; r < 4; ++r)
            qo[(bh * 2048 + sI + r) * 64 + dd] = f2bf((acc[ms][ns][r] + bcol) * QSCALE);
        } else if (which == 1) {
#pragma unroll
          for (int r = 0; r < 4; ++r)
            ko[(bh * 2048 + sI + r) * 64 + dd] = f2bf(acc[ms][ns][r] + bcol);
        } else {
          ushort4 pk;
          pk.x = f2bf(acc[ms][ns][0] + bcol);
          pk.y = f2bf(acc[ms][ns][1] + bcol);
          pk.z = f2bf(acc[ms][ns][2] + bcol);
          pk.w = f2bf(acc[ms][ns][3] + bcol);
          *(ushort4*)(vto + (bh * 64 + dd) * 2048 + sI) = pk;
        }
      }
    }
  }
}

// ---------------- flash attention (Q=128/block, split-KV z=4, dbuf K/V) -------------
// grid (S/128, B*H, 4). 4 waves; each wave owns 32 q rows (2 m-subtiles).
// Softmax-lite (no max; q pre-scaled). Each z-chunk: 8 KV tiles of 64.
// Unnormalized bf16 partial O + fp32 denoms; attn_combine_k merges 4 partials.
__global__ __launch_bounds__(256) void attn_kernel(
    const u16* __restrict__ q, const u16* __restrict__ k,
    const u16* __restrict__ vT, u16* __restrict__ opart,
    float* __restrict__ lpart) {
  __shared__ __align__(16) u16 lsK[2 * 64 * 64];  // [buf][s][d], swizzled
  __shared__ __align__(16) u16 lsV[2 * 64 * 64];  // [buf][d][s], swizzled
  __shared__ __align__(16) u16 lsP[4][32 * 64];   // per-wave [m 0..31][j], swizzled
  const int tid = threadIdx.x;
  const int w = tid >> 6, lane = tid & 63;
  const int lrow = lane & 15, quad = lane >> 4;
  const int bh = blockIdx.y;
  const int b = bh / 12, h = bh - b * 12;
  const int q0 = blockIdx.x * 128;
  const int z = blockIdx.z;
  const int kvbeg = z * (2048 / KVSPLIT);

  const u16* qbase = q + (size_t)bh * 2048 * 64;
  const u16* kbase = k + (size_t)bh * 2048 * 64;
  const u16* vbase = vT + (size_t)bh * 64 * 2048;

  bf16x8 qf[2][2];
#pragma unroll
  for (int m = 0; m < 2; ++m) {
    const int qrow = q0 + w * 32 + m * 16 + lrow;
    qf[m][0] = *(const bf16x8*)(qbase + (size_t)qrow * 64 + quad * 8);
    qf[m][1] = *(const bf16x8*)(qbase + (size_t)qrow * 64 + 32 + quad * 8);
  }

  float lsum[2][4] = {{0.f, 0.f, 0.f, 0.f}, {0.f, 0.f, 0.f, 0.f}};
  f32x4 oacc[2][4];
#pragma unroll
  for (int m = 0; m < 2; ++m)
#pragma unroll
    for (int d = 0; d < 4; ++d) oacc[m][d] = (f32x4){0.f, 0.f, 0.f, 0.f};

  const int off = tid * 16;
  const int srow = off >> 7;
  const int schunk = (off >> 4) & 7;
  const int sxc = schunk ^ (srow & 7);
  const int ksrc = srow * 64 + sxc * 8;
  const int vsrc0 = srow * 2048 + sxc * 8;

  const int c0 = quad ^ (lrow & 7);
  const int rd0 = c0 * 8, rd1 = (c0 ^ 4) * 8;

  u16* const lsPw = &lsP[w][0];
  const int jhi_base = lrow >> 3, jlo = lrow & 7;

  auto stage = [&](int kt, int buf) {
    char* dk = (char*)(lsK + buf * 4096);
    char* dv = (char*)(lsV + buf * 4096);
    GLDS16(kbase + (size_t)kt * 64 + ksrc, dk + off);
    GLDS16(kbase + (size_t)(kt + 32) * 64 + ksrc, dk + 4096 + off);
    GLDS16(vbase + vsrc0 + kt, dv + off);
    GLDS16(vbase + vsrc0 + kt + 32 * 2048, dv + 4096 + off);
  };

  const int ntiles = 2048 / KVSPLIT / 64;  // 8
  stage(kvbeg, 0);
  for (int t = 0; t < ntiles; ++t) {
    __syncthreads();
    if (t + 1 < ntiles) stage(kvbeg + (t + 1) * 64, (t + 1) & 1);
    const u16* Kb = lsK + (t & 1) * 4096;
    const u16* Vb = lsV + (t & 1) * 4096;

    f32x4 sc[2][4];
#pragma unroll
    for (int ns = 0; ns < 4; ++ns) {
      const u16* kr = Kb + (ns * 16 + lrow) * 64;
      bf16x8 kf0 = *(const bf16x8*)(kr + rd0);
      bf16x8 kf1 = *(const bf16x8*)(kr + rd1);
#pragma unroll
      for (int m = 0; m < 2; ++m) {
        sc[m][ns] = (f32x4){0.f, 0.f, 0.f, 0.f};
        sc[m][ns] = MFMA_BF16(qf[m][0], kf0, sc[m][ns]);
        sc[m][ns] = MFMA_BF16(qf[m][1], kf1, sc[m][ns]);
      }
    }

#pragma unroll
    for (int m = 0; m < 2; ++m)
#pragma unroll
      for (int ns = 0; ns < 4; ++ns) {
        const int jhi = ns * 2 + jhi_base;
#pragma unroll
        for (int r = 0; r < 4; ++r) {
          float p = __builtin_amdgcn_exp2f(sc[m][ns][r]);
          lsum[m][r] += p;
          union { float f; unsigned u; } cv; cv.f = p;
          const int row7 = (quad * 4 + r) & 7;
          lsPw[(m * 16 + quad * 4 + r) * 64 + ((jhi ^ row7) * 8) + jlo] =
              (u16)(cv.u >> 16);
        }
      }

    // PV (wave-private P: same-wave DS ordering, no barrier needed)
#pragma unroll
    for (int d = 0; d < 4; ++d) {
      const u16* vr = Vb + (d * 16 + lrow) * 64;
      bf16x8 vf0 = *(const bf16x8*)(vr + rd0);
      bf16x8 vf1 = *(const bf16x8*)(vr + rd1);
#pragma unroll
      for (int m = 0; m < 2; ++m) {
        const u16* pr = lsPw + (m * 16 + lrow) * 64;
        bf16x8 pf0 = *(const bf16x8*)(pr + rd0);
        bf16x8 pf1 = *(const bf16x8*)(pr + rd1);
        oacc[m][d] = MFMA_BF16(pf0, vf0, oacc[m][d]);
        oacc[m][d] = MFMA_BF16(pf1, vf1, oacc[m][d]);
      }
    }
  }

#pragma unroll
  for (int m = 0; m < 2; ++m)
#pragma unroll
    for (int r = 0; r < 4; ++r) {
#pragma unroll
      for (int mm = 1; mm <= 8; mm <<= 1)
        lsum[m][r] += __shfl_xor(lsum[m][r], mm);
    }

  u16* const op = opart + (size_t)z * PSTRIDE;
#pragma unroll
  for (int m = 0; m < 2; ++m) {
    const int srow_out = q0 + w * 32 + m * 16 + quad * 4;
#pragma unroll
    for (int d = 0; d < 4; ++d)
#pragma unroll
      for (int r = 0; r < 4; ++r)
        op[(size_t)(b * 2048 + srow_out + r) * 768 + h * 64 + d * 16 + lrow] =
            f2bf(oacc[m][d][r]);
    if (lrow == 0) {
#pragma unroll
      for (int r = 0; r < 4; ++r)
        lpart[(size_t)(z * 24 + bh) * 2048 + srow_out + r] = lsum[m][r];
    }
  }
}

// ctx = (sum_z o_z) / (sum_z l_z), bf16; vectorized x4
__global__ __launch_bounds__(256) void attn_combine_k(
    const u16* __restrict__ op, const float* __restrict__ lp,
    u16* __restrict__ ctx) {
  const unsigned idx = (blockIdx.x * 256u + threadIdx.x) * 4u;
  const unsigned row = idx / 768u;
  const unsigned c = idx - row * 768u;
  const int b = row >> 11, s = row & 2047;
  const int h = c >> 6;
  const size_t li = (size_t)(b * 12 + h) * 2048 + s;
  float l = 0.f;
  float sx = 0.f, sy = 0.f, sz = 0.f, sw = 0.f;
#pragma unroll
  for (int p = 0; p < KVSPLIT; ++p) {
    l += lp[(size_t)p * 24 * 2048 + li];
    ushort4 o = *(const ushort4*)(op + (size_t)p * PSTRIDE + idx);
    sx += bf2f(o.x); sy += bf2f(o.y); sz += bf2f(o.z); sw += bf2f(o.w);
  }
  const float rinv = 1.f / l;
  ushort4 out;
  out.x = f2bf(sx * rinv); out.y = f2bf(sy * rinv);
  out.z = f2bf(sz * rinv); out.w = f2bf(sw * rinv);
  *(ushort4*)(ctx + idx) = out;
}

// ---------------- bf16-partial-sum + bias + residual + layernorm ----------------
__global__ __launch_bounds__(256) void ln_kernel(
    const u16* __restrict__ parts, int nparts, const float* __restrict__ bias,
    const float* __restrict__ res, const float* __restrict__ g,
    const float* __restrict__ bb, float* __restrict__ outf, u16* __restrict__ outb) {
  const int row = blockIdx.x;
  const int tid = threadIdx.x;
  const float* pr = res + (size_t)row * 768;
  float v[3], s = 0.f, s2 = 0.f;
#pragma unroll
  for (int j = 0; j < 3; ++j) {
    const int c = tid + j * 256;
    float t = bias[c] + pr[c];
    for (int p = 0; p < nparts; ++p)
      t += bf2f(parts[p * PSTRIDE + (size_t)row * 768 + c]);
    v[j] = t; s += t; s2 += t * t;
  }
#pragma unroll
  for (int m = 32; m > 0; m >>= 1) {
    s += __shfl_xor(s, m);
    s2 += __shfl_xor(s2, m);
  }
  __shared__ float red[8];
  const int w = tid >> 6, lane = tid & 63;
  if (lane == 0) { red[w] = s; red[4 + w] = s2; }
  __syncthreads();
  s = red[0] + red[1] + red[2] + red[3];
  s2 = red[4] + red[5] + red[6] + red[7];
  const float mu = s * (1.f / 768.f);
  const float var = s2 * (1.f / 768.f) - mu * mu;
  const float rstd = rsqrtf(var + 1e-5f);
#pragma unroll
  for (int j = 0; j < 3; ++j) {
    const int c = tid + j * 256;
    const float y = (v[j] - mu) * rstd * g[c] + bb[c];
    if (outf) outf[(size_t)row * 768 + c] = y;
    if (outb) outb[(size_t)row * 768 + c] = f2bf(y);
  }
}

// ---------------- launch ----------------
extern "C" void kernel_launch(void* const* d_in, const int* in_sizes, int n_in,
                              void* d_out, int out_size, void* d_ws, size_t ws_size,
                              hipStream_t stream) {
  const float* x    = (const float*)d_in[0];
  const float* Wq   = (const float*)d_in[1];
  const float* bq   = (const float*)d_in[2];
  const float* Wk   = (const float*)d_in[3];
  const float* bk   = (const float*)d_in[4];
  const float* Wv   = (const float*)d_in[5];
  const float* bv   = (const float*)d_in[6];
  const float* Wo   = (const float*)d_in[7];
  const float* bo   = (const float*)d_in[8];
  const float* W1   = (const float*)d_in[9];
  const float* b1   = (const float*)d_in[10];
  const float* W2   = (const float*)d_in[11];
  const float* b2   = (const float*)d_in[12];
  const float* ln1g = (const float*)d_in[13];
  const float* ln1b = (const float*)d_in[14];
  const float* ln2g = (const float*)d_in[15];
  const float* ln2b = (const float*)d_in[16];

  char* ws = (char*)d_ws;
  size_t off = 0;
  auto alloc = [&](size_t bytes) {
    void* p = ws + off;
    off += (bytes + 255) & ~(size_t)255;
    return p;
  };
  // persistent weights (14.2 MB)
  u16*  WqkvT = (u16*)alloc(2304ull * 768 * 2);
  u16*  WoT   = (u16*)alloc(768ull * 768 * 2);
  u16*  W1T   = (u16*)alloc(3072ull * 768 * 2);
  u16*  W2T   = (u16*)alloc(768ull * 3072 * 2);
  float* bqkv = (float*)alloc(2304 * 4);
  // bigbase region: [xb qb kb vtb] (25.2 MB). Aliased later by:
  //   wop  (Wo bf16 partials z=2, 12.6 MB)  — xb..vtb dead after combine
  //   f2bp (FFN2 bf16 partials z=4, 25.2 MB) — wop dead after ln1
  char* bigbase = (char*)alloc(0);
  u16*  xb    = (u16*)alloc(4096ull * 768 * 2);
  u16*  qb    = (u16*)alloc(24ull * 2048 * 64 * 2);
  u16*  kb    = (u16*)alloc(24ull * 2048 * 64 * 2);
  u16*  vtb   = (u16*)alloc(24ull * 64 * 2048 * 2);
  u16*  ctx   = (u16*)alloc(4096ull * 768 * 2);
  float* lpart = (float*)alloc((size_t)KVSPLIT * 24 * 2048 * 4);
  // tail (contiguous 44 MB): hbuf | hb | f1
  float* hbuf  = (float*)alloc(4096ull * 768 * 4);
  u16*  hb    = (u16*)alloc(4096ull * 768 * 2);
  u16*  f1    = (u16*)alloc(4096ull * 3072 * 2);
  // aliases (no fresh allocation; total ws usage 90.4 MB < R11's proven 102.6 MB):
  u16*  wop   = (u16*)bigbase;      // dead xb..vtb after attention combine
  u16*  f2bp  = (u16*)bigbase;      // dead wop after ln1
  u16*  opart = (u16*)hbuf;         // attn partials (25.2 MB) over hbuf+hb+head of f1,
                                    // all dead during attention; consumed before ln1/FFN1 write them

  // one fused prep launch: 6 transposes + bias concat + x convert
  prep_weights_k<<<9993, 256, 0, stream>>>(Wq, Wk, Wv, Wo, W1, W2, bq, bk, bv, x,
                                           WqkvT, WoT, W1T, W2T, bqkv, xb);

  // QKV: M=4096 N=2304 K=768
  gemm_bt<0><<<dim3(18, 32, 1), 256, 0, stream>>>(xb, WqkvT, bqkv, 4096, 2304, 768, 768,
                                                  nullptr, nullptr, qb, kb, vtb);
  // attention: Q=128/block, split-KV z=4, partials into opart (alias of hbuf..)
  attn_kernel<<<dim3(16, 24, KVSPLIT), 256, 0, stream>>>(qb, kb, vtb, opart, lpart);
  attn_combine_k<<<3072, 256, 0, stream>>>(opart, lpart, ctx);
  // Wo: split-K z=2 -> 2 bf16 partials in wop (over dead xb/qb)
  gemm_bt<3><<<dim3(6, 32, 2), 256, 0, stream>>>(ctx, WoT, nullptr, 4096, 768, 768, 384,
                                                 nullptr, wop, nullptr, nullptr, nullptr);
  ln_kernel<<<4096, 256, 0, stream>>>(wop, 2, bo, x, ln1g, ln1b, hbuf, hb);
  // FFN1: M=4096 N=3072 K=768, GELU epilogue
  gemm_bt<2><<<dim3(24, 32, 1), 256, 0, stream>>>(hb, W1T, b1, 4096, 3072, 768, 768,
                                                  nullptr, f1, nullptr, nullptr, nullptr);
  // FFN2: split-K z=4 -> 4 bf16 partials in f2bp (over dead wop/bigbase)
  gemm_bt<3><<<dim3(6, 32, 4), 256, 0, stream>>>(f1, W2T, nullptr, 4096, 768, 3072, 768,
                                                 nullptr, f2bp, nullptr, nullptr, nullptr);
  ln_kernel<<<4096, 256, 0, stream>>>(f2bp, 4, b2, hbuf, ln2g, ln2b, (float*)d_out, nullptr);
}

// Round 15
// 299.415 us; speedup vs baseline: 1.1730x; 1.0059x over previous
//
#include <hip/hip_runtime.h>
#include <hip/hip_bf16.h>
#include <cstdint>
#include <cstddef>

typedef unsigned short u16;
typedef __bf16 bf16x8 __attribute__((ext_vector_type(8)));
typedef float f32x4 __attribute__((ext_vector_type(4)));

#define MFMA_BF16(a, b, c) __builtin_amdgcn_mfma_f32_16x16x32_bf16((a), (b), (c), 0, 0, 0)

// global -> LDS async copy, 16B per lane. LDS layout must be wave-uniform base + lane*16.
#define GLDS16(g, l)                                                        \
  __builtin_amdgcn_global_load_lds(                                         \
      (__attribute__((address_space(1))) void*)(void*)(g),                  \
      (__attribute__((address_space(3))) void*)(void*)(l), 16, 0, 0)

// scale folded into q at QKV epilogue: 1/sqrt(64) * log2(e), so softmax uses exp2 directly
#define QSCALE 0.18033688011112042f
#define PSTRIDE ((size_t)4096 * 768)
#define KVSPLIT 2   // z=2 proven best (R11 298.2); z=4 regressed (R14 301.2)

__device__ __forceinline__ u16 f2bf(float x) {
  union { float f; unsigned u; } c; c.f = x;
  unsigned u = c.u;
  unsigned r = (u + 0x7fffu + ((u >> 16) & 1u)) >> 16;  // RNE
  return (u16)r;
}
__device__ __forceinline__ float bf2f(u16 x) {
  union { unsigned u; float f; } c; c.u = (unsigned)x << 16; return c.f;
}

// ---------------- fused prep kernel: 6 transposes + bias concat + x convert ----------
__global__ __launch_bounds__(256) void prep_weights_k(
    const float* __restrict__ Wq, const float* __restrict__ Wk,
    const float* __restrict__ Wv, const float* __restrict__ Wo,
    const float* __restrict__ W1, const float* __restrict__ W2,
    const float* __restrict__ bq, const float* __restrict__ bk,
    const float* __restrict__ bv, const float* __restrict__ x,
    u16* __restrict__ WqkvT, u16* __restrict__ WoT,
    u16* __restrict__ W1T, u16* __restrict__ W2T, float* __restrict__ bqkv,
    u16* __restrict__ xb) {
  const int id = blockIdx.x;
  if (id >= 6921) {  // x convert, 4 elems/thread
    const int i = ((id - 6921) * 256 + threadIdx.x) * 4;
    const float4 v = *(const float4*)(x + i);
    ushort4 o;
    o.x = f2bf(v.x); o.y = f2bf(v.y); o.z = f2bf(v.z); o.w = f2bf(v.w);
    *(ushort4*)(xb + i) = o;
    return;
  }
  if (id >= 6912) {  // bias concat
    int i = (id - 6912) * 256 + threadIdx.x;
    if (i < 768) bqkv[i] = bq[i];
    else if (i < 1536) bqkv[i] = bk[i - 768];
    else if (i < 2304) bqkv[i] = bv[i - 1536];
    return;
  }
  const float* in; u16* out; int K, N, bx, by;
  if (id < 2304) {
    const int mat = id / 576, t = id - mat * 576;
    in = (mat == 0) ? Wq : (mat == 1) ? Wk : (mat == 2) ? Wv : Wo;
    out = (mat == 0) ? WqkvT : (mat == 1) ? WqkvT + 768 * 768
        : (mat == 2) ? WqkvT + 2 * 768 * 768 : WoT;
    K = 768; N = 768; bx = (t % 24) * 32; by = (t / 24) * 32;
  } else if (id < 4608) {
    const int t = id - 2304;
    in = W1; out = W1T; K = 768; N = 3072;
    bx = (t % 96) * 32; by = (t / 96) * 32;
  } else {
    const int t = id - 4608;
    in = W2; out = W2T; K = 3072; N = 768;
    bx = (t % 24) * 32; by = (t / 24) * 32;
  }
  __shared__ float tile[32][33];
  const int tx = threadIdx.x & 31, ty = threadIdx.x >> 5;
#pragma unroll
  for (int j = 0; j < 32; j += 8)
    tile[ty + j][tx] = in[(size_t)(by + ty + j) * N + bx + tx];
  __syncthreads();
#pragma unroll
  for (int j = 0; j < 32; j += 8)
    out[(size_t)(bx + ty + j) * K + by + tx] = f2bf(tile[tx][ty + j]);
}

// ---------------- GEMM: C = A[MxK] @ B^T[NxK]^T (+ bias) ----------------
// [LOCKED: R9/R11-proven best by GRAPH total. BK=32 dbuf, one barrier/iter,
//  32 KB LDS, line-pair swizzle (0 conflicts).]
// 128x128 tile, 4 waves (2x2), wave = 64x64 = 4x4 mfma 16x16x32 subtiles.
// EPI: 0 = QKV scatter   2 = gelu->bf16   3 = BF16 split-K partial
template <int EPI>
__global__ __launch_bounds__(256) void gemm_bt(
    const u16* __restrict__ A, const u16* __restrict__ BT,
    const float* __restrict__ bias, int M, int N, int K, int kchunk,
    float* __restrict__ outf, u16* __restrict__ outb,
    u16* __restrict__ qo, u16* __restrict__ ko, u16* __restrict__ vto) {
  __shared__ __align__(16) u16 lsA[2 * 128 * 32];
  __shared__ __align__(16) u16 lsB[2 * 128 * 32];
  const int tid = threadIdx.x;
  const int w = tid >> 6, lane = tid & 63;
  const int wm = w & 1, wn = w >> 1;
  const int lrow = lane & 15, quad = lane >> 4;
  const int m0 = blockIdx.y * 128, n0 = blockIdx.x * 128;
  const int kbeg = blockIdx.z * kchunk;

  f32x4 acc[4][4];
#pragma unroll
  for (int i = 0; i < 4; ++i)
#pragma unroll
    for (int j = 0; j < 4; ++j) acc[i][j] = (f32x4){0.f, 0.f, 0.f, 0.f};

  // staging: thread covers 16 B at LDS byte tid*16 of each 4 KB half-tile
  const int off = tid * 16;
  const int line = tid >> 3;           // 128-B line (2 rows of 64 B)
  const int slotp = tid & 7;           // 16-B slot within line
  const int p = slotp ^ (line & 7);    // logical pos = (row&1)*4 + chunk
  const int srow = line * 2 + (p >> 2);
  const int scol = (p & 3) * 8;        // u16 col within BK=32

  const u16* ga0 = A + (size_t)(m0 + srow) * K + scol;
  const u16* gb0 = BT + (size_t)(n0 + srow) * K + scol;

  auto stage = [&](int k0, int buf) {
    char* da = (char*)(lsA + buf * 4096);
    char* db = (char*)(lsB + buf * 4096);
    GLDS16(ga0 + k0, da + off);
    GLDS16(ga0 + k0 + (size_t)64 * K, da + 4096 + off);
    GLDS16(gb0 + k0, db + off);
    GLDS16(gb0 + k0 + (size_t)64 * K, db + 4096 + off);
  };

  // fragment read: row = wbase + ms*16 + lrow, chunk = quad
  const int lline = lrow >> 1;
  const int lslot = (((lrow & 1) << 2) + quad) ^ ((lrow >> 1) & 7);
  const int rdoff = lslot * 8;

  const int niter = kchunk >> 5;
  stage(kbeg, 0);
  for (int t = 0; t < niter; ++t) {
    __syncthreads();  // drains buf[t] prefetch (covered by compute of t-1)
    if (t + 1 < niter) stage(kbeg + (t + 1) * 32, (t + 1) & 1);
    const u16* Ab = lsA + (t & 1) * 4096;
    const u16* Bb = lsB + (t & 1) * 4096;
    bf16x8 af[4], bfr[4];
#pragma unroll
    for (int ms = 0; ms < 4; ++ms)
      af[ms] = *(const bf16x8*)&Ab[(wm * 32 + ms * 8 + lline) * 64 + rdoff];
#pragma unroll
    for (int ns = 0; ns < 4; ++ns)
      bfr[ns] = *(const bf16x8*)&Bb[(wn * 32 + ns * 8 + lline) * 64 + rdoff];
#pragma unroll
    for (int ms = 0; ms < 4; ++ms)
#pragma unroll
      for (int ns = 0; ns < 4; ++ns)
        acc[ms][ns] = MFMA_BF16(af[ms], bfr[ns], acc[ms][ns]);
  }

  u16* const pb = (EPI == 3) ? outb + (size_t)blockIdx.z * PSTRIDE : outb;
#pragma unroll
  for (int ms = 0; ms < 4; ++ms) {
    const int rbase = m0 + wm * 64 + ms * 16 + quad * 4;
#pragma unroll
    for (int ns = 0; ns < 4; ++ns) {
      const int col = n0 + wn * 64 + ns * 16 + lrow;
      if constexpr (EPI == 3) {
#pragma unroll
        for (int r = 0; r < 4; ++r)
          pb[(size_t)(rbase + r) * N + col] = f2bf(acc[ms][ns][r]);
      } else if constexpr (EPI == 2) {
        const float bcol = bias[col];
#pragma unroll
        for (int r = 0; r < 4; ++r) {
          float v = acc[ms][ns][r] + bcol;
          float g = 0.5f * v * (1.0f + erff(v * 0.7071067811865476f));
          outb[(size_t)(rbase + r) * N + col] = f2bf(g);
        }
      } else {  // QKV scatter
        const float bcol = bias[col];
        const int which = col / 768;
        const int rem = col - which * 768;
        const int hh = rem >> 6, dd = rem & 63;
        const int bI = rbase >> 11, sI = rbase & 2047;
        const size_t bh = (size_t)bI * 12 + hh;
        if (which == 0) {
#pragma unroll
          for (int r = 0; r < 4; ++r)
            qo[(bh * 2048 + sI + r) * 64 + dd] = f2bf((acc[ms][ns][r] + bcol) * QSCALE);
        } else if (which == 1) {
#pragma unroll
          for (int r = 0; r < 4; ++r)
            ko[(bh * 2048 + sI + r) * 64 + dd] = f2bf(acc[ms][ns][r] + bcol);
        } else {
          ushort4 pk;
          pk.x = f2bf(acc[ms][ns][0] + bcol);
          pk.y = f2bf(acc[ms][ns][1] + bcol);
          pk.z = f2bf(acc[ms][ns][2] + bcol);
          pk.w = f2bf(acc[ms][ns][3] + bcol);
          *(ushort4*)(vto + (bh * 64 + dd) * 2048 + sI) = pk;
        }
      }
    }
  }
}

// ---------------- flash attention (Q=128/block, split-KV z=2, dbuf K/V) -------------
// grid (S/128, B*H, 2). 4 waves; each wave owns 32 q rows (2 m-subtiles),
// reusing each K/V fragment across both. Softmax-lite (no max; q pre-scaled).
// Unnormalized bf16 partial O + fp32 denoms; attn_combine_k merges 2 partials.
// [R11-proven: 46 us, 0 bank conflicts. z=4 and S^T variants regressed.]
__global__ __launch_bounds__(256) void attn_kernel(
    const u16* __restrict__ q, const u16* __restrict__ k,
    const u16* __restrict__ vT, u16* __restrict__ opart,
    float* __restrict__ lpart) {
  __shared__ __align__(16) u16 lsK[2 * 64 * 64];  // [buf][s][d], swizzled
  __shared__ __align__(16) u16 lsV[2 * 64 * 64];  // [buf][d][s], swizzled
  __shared__ __align__(16) u16 lsP[4][32 * 64];   // per-wave [m 0..31][j], swizzled
  const int tid = threadIdx.x;
  const int w = tid >> 6, lane = tid & 63;
  const int lrow = lane & 15, quad = lane >> 4;
  const int bh = blockIdx.y;
  const int b = bh / 12, h = bh - b * 12;
  const int q0 = blockIdx.x * 128;
  const int z = blockIdx.z;
  const int kvbeg = z * (2048 / KVSPLIT);

  const u16* qbase = q + (size_t)bh * 2048 * 64;
  const u16* kbase = k + (size_t)bh * 2048 * 64;
  const u16* vbase = vT + (size_t)bh * 64 * 2048;

  bf16x8 qf[2][2];
#pragma unroll
  for (int m = 0; m < 2; ++m) {
    const int qrow = q0 + w * 32 + m * 16 + lrow;
    qf[m][0] = *(const bf16x8*)(qbase + (size_t)qrow * 64 + quad * 8);
    qf[m][1] = *(const bf16x8*)(qbase + (size_t)qrow * 64 + 32 + quad * 8);
  }

  float lsum[2][4] = {{0.f, 0.f, 0.f, 0.f}, {0.f, 0.f, 0.f, 0.f}};
  f32x4 oacc[2][4];
#pragma unroll
  for (int m = 0; m < 2; ++m)
#pragma unroll
    for (int d = 0; d < 4; ++d) oacc[m][d] = (f32x4){0.f, 0.f, 0.f, 0.f};

  const int off = tid * 16;
  const int srow = off >> 7;
  const int schunk = (off >> 4) & 7;
  const int sxc = schunk ^ (srow & 7);
  const int ksrc = srow * 64 + sxc * 8;
  const int vsrc0 = srow * 2048 + sxc * 8;

  const int c0 = quad ^ (lrow & 7);
  const int rd0 = c0 * 8, rd1 = (c0 ^ 4) * 8;

  u16* const lsPw = &lsP[w][0];
  const int jhi_base = lrow >> 3, jlo = lrow & 7;

  auto stage = [&](int kt, int buf) {
    char* dk = (char*)(lsK + buf * 4096);
    char* dv = (char*)(lsV + buf * 4096);
    GLDS16(kbase + (size_t)kt * 64 + ksrc, dk + off);
    GLDS16(kbase + (size_t)(kt + 32) * 64 + ksrc, dk + 4096 + off);
    GLDS16(vbase + vsrc0 + kt, dv + off);
    GLDS16(vbase + vsrc0 + kt + 32 * 2048, dv + 4096 + off);
  };

  const int ntiles = 2048 / KVSPLIT / 64;  // 16
  stage(kvbeg, 0);
  for (int t = 0; t < ntiles; ++t) {
    __syncthreads();
    if (t + 1 < ntiles) stage(kvbeg + (t + 1) * 64, (t + 1) & 1);
    const u16* Kb = lsK + (t & 1) * 4096;
    const u16* Vb = lsV + (t & 1) * 4096;

    f32x4 sc[2][4];
#pragma unroll
    for (int ns = 0; ns < 4; ++ns) {
      const u16* kr = Kb + (ns * 16 + lrow) * 64;
      bf16x8 kf0 = *(const bf16x8*)(kr + rd0);
      bf16x8 kf1 = *(const bf16x8*)(kr + rd1);
#pragma unroll
      for (int m = 0; m < 2; ++m) {
        sc[m][ns] = (f32x4){0.f, 0.f, 0.f, 0.f};
        sc[m][ns] = MFMA_BF16(qf[m][0], kf0, sc[m][ns]);
        sc[m][ns] = MFMA_BF16(qf[m][1], kf1, sc[m][ns]);
      }
    }

#pragma unroll
    for (int m = 0; m < 2; ++m)
#pragma unroll
      for (int ns = 0; ns < 4; ++ns) {
        const int jhi = ns * 2 + jhi_base;
#pragma unroll
        for (int r = 0; r < 4; ++r) {
          float p = __builtin_amdgcn_exp2f(sc[m][ns][r]);
          lsum[m][r] += p;
          union { float f; unsigned u; } cv; cv.f = p;
          const int row7 = (quad * 4 + r) & 7;
          lsPw[(m * 16 + quad * 4 + r) * 64 + ((jhi ^ row7) * 8) + jlo] =
              (u16)(cv.u >> 16);
        }
      }

    // PV (wave-private P: same-wave DS ordering, no barrier needed)
#pragma unroll
    for (int d = 0; d < 4; ++d) {
      const u16* vr = Vb + (d * 16 + lrow) * 64;
      bf16x8 vf0 = *(const bf16x8*)(vr + rd0);
      bf16x8 vf1 = *(const bf16x8*)(vr + rd1);
#pragma unroll
      for (int m = 0; m < 2; ++m) {
        const u16* pr = lsPw + (m * 16 + lrow) * 64;
        bf16x8 pf0 = *(const bf16x8*)(pr + rd0);
        bf16x8 pf1 = *(const bf16x8*)(pr + rd1);
        oacc[m][d] = MFMA_BF16(pf0, vf0, oacc[m][d]);
        oacc[m][d] = MFMA_BF16(pf1, vf1, oacc[m][d]);
      }
    }
  }

#pragma unroll
  for (int m = 0; m < 2; ++m)
#pragma unroll
    for (int r = 0; r < 4; ++r) {
#pragma unroll
      for (int mm = 1; mm <= 8; mm <<= 1)
        lsum[m][r] += __shfl_xor(lsum[m][r], mm);
    }

  u16* const op = opart + (size_t)z * PSTRIDE;
#pragma unroll
  for (int m = 0; m < 2; ++m) {
    const int srow_out = q0 + w * 32 + m * 16 + quad * 4;
#pragma unroll
    for (int d = 0; d < 4; ++d)
#pragma unroll
      for (int r = 0; r < 4; ++r)
        op[(size_t)(b * 2048 + srow_out + r) * 768 + h * 64 + d * 16 + lrow] =
            f2bf(oacc[m][d][r]);
    if (lrow == 0) {
#pragma unroll
      for (int r = 0; r < 4; ++r)
        lpart[(size_t)(z * 24 + bh) * 2048 + srow_out + r] = lsum[m][r];
    }
  }
}

// ctx = (sum_z o_z) / (sum_z l_z), bf16; vectorized x4
__global__ __launch_bounds__(256) void attn_combine_k(
    const u16* __restrict__ op, const float* __restrict__ lp,
    u16* __restrict__ ctx) {
  const unsigned idx = (blockIdx.x * 256u + threadIdx.x) * 4u;
  const unsigned row = idx / 768u;
  const unsigned c = idx - row * 768u;
  const int b = row >> 11, s = row & 2047;
  const int h = c >> 6;
  const size_t li = (size_t)(b * 12 + h) * 2048 + s;
  float l = 0.f;
  float sx = 0.f, sy = 0.f, sz = 0.f, sw = 0.f;
#pragma unroll
  for (int p = 0; p < KVSPLIT; ++p) {
    l += lp[(size_t)p * 24 * 2048 + li];
    ushort4 o = *(const ushort4*)(op + (size_t)p * PSTRIDE + idx);
    sx += bf2f(o.x); sy += bf2f(o.y); sz += bf2f(o.z); sw += bf2f(o.w);
  }
  const float rinv = 1.f / l;
  ushort4 out;
  out.x = f2bf(sx * rinv); out.y = f2bf(sy * rinv);
  out.z = f2bf(sz * rinv); out.w = f2bf(sw * rinv);
  *(ushort4*)(ctx + idx) = out;
}

// ---------------- bf16-partial-sum + bias + residual + layernorm ----------------
__global__ __launch_bounds__(256) void ln_kernel(
    const u16* __restrict__ parts, int nparts, const float* __restrict__ bias,
    const float* __restrict__ res, const float* __restrict__ g,
    const float* __restrict__ bb, float* __restrict__ outf, u16* __restrict__ outb) {
  const int row = blockIdx.x;
  const int tid = threadIdx.x;
  const float* pr = res + (size_t)row * 768;
  float v[3], s = 0.f, s2 = 0.f;
#pragma unroll
  for (int j = 0; j < 3; ++j) {
    const int c = tid + j * 256;
    float t = bias[c] + pr[c];
    for (int p = 0; p < nparts; ++p)
      t += bf2f(parts[p * PSTRIDE + (size_t)row * 768 + c]);
    v[j] = t; s += t; s2 += t * t;
  }
#pragma unroll
  for (int m = 32; m > 0; m >>= 1) {
    s += __shfl_xor(s, m);
    s2 += __shfl_xor(s2, m);
  }
  __shared__ float red[8];
  const int w = tid >> 6, lane = tid & 63;
  if (lane == 0) { red[w] = s; red[4 + w] = s2; }
  __syncthreads();
  s = red[0] + red[1] + red[2] + red[3];
  s2 = red[4] + red[5] + red[6] + red[7];
  const float mu = s * (1.f / 768.f);
  const float var = s2 * (1.f / 768.f) - mu * mu;
  const float rstd = rsqrtf(var + 1e-5f);
#pragma unroll
  for (int j = 0; j < 3; ++j) {
    const int c = tid + j * 256;
    const float y = (v[j] - mu) * rstd * g[c] + bb[c];
    if (outf) outf[(size_t)row * 768 + c] = y;
    if (outb) outb[(size_t)row * 768 + c] = f2bf(y);
  }
}

// ---------------- launch ----------------
extern "C" void kernel_launch(void* const* d_in, const int* in_sizes, int n_in,
                              void* d_out, int out_size, void* d_ws, size_t ws_size,
                              hipStream_t stream) {
  const float* x    = (const float*)d_in[0];
  const float* Wq   = (const float*)d_in[1];
  const float* bq   = (const float*)d_in[2];
  const float* Wk   = (const float*)d_in[3];
  const float* bk   = (const float*)d_in[4];
  const float* Wv   = (const float*)d_in[5];
  const float* bv   = (const float*)d_in[6];
  const float* Wo   = (const float*)d_in[7];
  const float* bo   = (const float*)d_in[8];
  const float* W1   = (const float*)d_in[9];
  const float* b1   = (const float*)d_in[10];
  const float* W2   = (const float*)d_in[11];
  const float* b2   = (const float*)d_in[12];
  const float* ln1g = (const float*)d_in[13];
  const float* ln1b = (const float*)d_in[14];
  const float* ln2g = (const float*)d_in[15];
  const float* ln2b = (const float*)d_in[16];

  char* ws = (char*)d_ws;
  size_t off = 0;
  auto alloc = [&](size_t bytes) {
    void* p = ws + off;
    off += (bytes + 255) & ~(size_t)255;
    return p;
  };
  // persistent weights (14.2 MB)
  u16*  WqkvT = (u16*)alloc(2304ull * 768 * 2);
  u16*  WoT   = (u16*)alloc(768ull * 768 * 2);
  u16*  W1T   = (u16*)alloc(3072ull * 768 * 2);
  u16*  W2T   = (u16*)alloc(768ull * 3072 * 2);
  float* bqkv = (float*)alloc(2304 * 4);
  // bigbase region: [xb qb kb vtb] (25.2 MB). Aliased later by:
  //   wop  (Wo bf16 partials z=2, 12.6 MB)  — xb..vtb dead after combine
  //   f2bp (FFN2 bf16 partials z=4, 25.2 MB) — wop dead after ln1
  char* bigbase = (char*)alloc(0);
  u16*  xb    = (u16*)alloc(4096ull * 768 * 2);
  u16*  qb    = (u16*)alloc(24ull * 2048 * 64 * 2);
  u16*  kb    = (u16*)alloc(24ull * 2048 * 64 * 2);
  u16*  vtb   = (u16*)alloc(24ull * 64 * 2048 * 2);
  u16*  ctx   = (u16*)alloc(4096ull * 768 * 2);
  float* lpart = (float*)alloc((size_t)KVSPLIT * 24 * 2048 * 4);
  // tail (contiguous): hbuf | hb | f1
  float* hbuf  = (float*)alloc(4096ull * 768 * 4);
  u16*  hb    = (u16*)alloc(4096ull * 768 * 2);
  u16*  f1    = (u16*)alloc(4096ull * 3072 * 2);
  // aliases (no fresh allocation; layout hardware-validated in R14):
  u16*  wop   = (u16*)bigbase;      // dead xb..vtb after attention combine
  u16*  f2bp  = (u16*)bigbase;      // dead wop after ln1
  u16*  opart = (u16*)hbuf;         // attn partials (z=2: 12.6 MB, exactly over hbuf),
                                    // dead during attention; consumed before ln1 writes hbuf

  // one fused prep launch: 6 transposes + bias concat + x convert
  prep_weights_k<<<9993, 256, 0, stream>>>(Wq, Wk, Wv, Wo, W1, W2, bq, bk, bv, x,
                                           WqkvT, WoT, W1T, W2T, bqkv, xb);

  // QKV: M=4096 N=2304 K=768
  gemm_bt<0><<<dim3(18, 32, 1), 256, 0, stream>>>(xb, WqkvT, bqkv, 4096, 2304, 768, 768,
                                                  nullptr, nullptr, qb, kb, vtb);
  // attention: Q=128/block, split-KV z=2, partials into opart (alias of hbuf)
  attn_kernel<<<dim3(16, 24, KVSPLIT), 256, 0, stream>>>(qb, kb, vtb, opart, lpart);
  attn_combine_k<<<3072, 256, 0, stream>>>(opart, lpart, ctx);
  // Wo: split-K z=2 -> 2 bf16 partials in wop (over dead xb/qb)
  gemm_bt<3><<<dim3(6, 32, 2), 256, 0, stream>>>(ctx, WoT, nullptr, 4096, 768, 768, 384,
                                                 nullptr, wop, nullptr, nullptr, nullptr);
  ln_kernel<<<4096, 256, 0, stream>>>(wop, 2, bo, x, ln1g, ln1b, hbuf, hb);
  // FFN1: M=4096 N=3072 K=768, GELU epilogue
  gemm_bt<2><<<dim3(24, 32, 1), 256, 0, stream>>>(hb, W1T, b1, 4096, 3072, 768, 768,
                                                  nullptr, f1, nullptr, nullptr, nullptr);
  // FFN2: split-K z=4 -> 4 bf16 partials in f2bp (over dead wop/bigbase)
  gemm_bt<3><<<dim3(6, 32, 4), 256, 0, stream>>>(f1, W2T, nullptr, 4096, 768, 3072, 768,
                                                 nullptr, f2bp, nullptr, nullptr, nullptr);
  ln_kernel<<<4096, 256, 0, stream>>>(f2bp, 4, b2, hbuf, ln2g, ln2b, (float*)d_out, nullptr);
}

// Round 16
// 297.055 us; speedup vs baseline: 1.1823x; 1.0079x over previous
//
#include <hip/hip_runtime.h>
#include <hip/hip_bf16.h>
#include <cstdint>
#include <cstddef>

typedef unsigned short u16;
typedef __bf16 bf16x8 __attribute__((ext_vector_type(8)));
typedef float f32x4 __attribute__((ext_vector_type(4)));

#define MFMA_BF16(a, b, c) __builtin_amdgcn_mfma_f32_16x16x32_bf16((a), (b), (c), 0, 0, 0)

// global -> LDS async copy, 16B per lane. LDS layout must be wave-uniform base + lane*16.
#define GLDS16(g, l)                                                        \
  __builtin_amdgcn_global_load_lds(                                         \
      (__attribute__((address_space(1))) void*)(void*)(g),                  \
      (__attribute__((address_space(3))) void*)(void*)(l), 16, 0, 0)

// scale folded into q at QKV epilogue: 1/sqrt(64) * log2(e), so softmax uses exp2 directly
#define QSCALE 0.18033688011112042f
#define PSTRIDE ((size_t)4096 * 768)
#define KVSPLIT 2   // z=2 proven best (R11 298.2); z=4 regressed (R14 301.2)

__device__ __forceinline__ u16 f2bf(float x) {
  union { float f; unsigned u; } c; c.f = x;
  unsigned u = c.u;
  unsigned r = (u + 0x7fffu + ((u >> 16) & 1u)) >> 16;  // RNE
  return (u16)r;
}
__device__ __forceinline__ float bf2f(u16 x) {
  union { unsigned u; float f; } c; c.u = (unsigned)x << 16; return c.f;
}

// ---------------- fused prep kernel: 6 transposes + bias concat + x convert ----------
__global__ __launch_bounds__(256) void prep_weights_k(
    const float* __restrict__ Wq, const float* __restrict__ Wk,
    const float* __restrict__ Wv, const float* __restrict__ Wo,
    const float* __restrict__ W1, const float* __restrict__ W2,
    const float* __restrict__ bq, const float* __restrict__ bk,
    const float* __restrict__ bv, const float* __restrict__ x,
    u16* __restrict__ WqkvT, u16* __restrict__ WoT,
    u16* __restrict__ W1T, u16* __restrict__ W2T, float* __restrict__ bqkv,
    u16* __restrict__ xb) {
  const int id = blockIdx.x;
  if (id >= 6921) {  // x convert, 4 elems/thread
    const int i = ((id - 6921) * 256 + threadIdx.x) * 4;
    const float4 v = *(const float4*)(x + i);
    ushort4 o;
    o.x = f2bf(v.x); o.y = f2bf(v.y); o.z = f2bf(v.z); o.w = f2bf(v.w);
    *(ushort4*)(xb + i) = o;
    return;
  }
  if (id >= 6912) {  // bias concat
    int i = (id - 6912) * 256 + threadIdx.x;
    if (i < 768) bqkv[i] = bq[i];
    else if (i < 1536) bqkv[i] = bk[i - 768];
    else if (i < 2304) bqkv[i] = bv[i - 1536];
    return;
  }
  const float* in; u16* out; int K, N, bx, by;
  if (id < 2304) {
    const int mat = id / 576, t = id - mat * 576;
    in = (mat == 0) ? Wq : (mat == 1) ? Wk : (mat == 2) ? Wv : Wo;
    out = (mat == 0) ? WqkvT : (mat == 1) ? WqkvT + 768 * 768
        : (mat == 2) ? WqkvT + 2 * 768 * 768 : WoT;
    K = 768; N = 768; bx = (t % 24) * 32; by = (t / 24) * 32;
  } else if (id < 4608) {
    const int t = id - 2304;
    in = W1; out = W1T; K = 768; N = 3072;
    bx = (t % 96) * 32; by = (t / 96) * 32;
  } else {
    const int t = id - 4608;
    in = W2; out = W2T; K = 3072; N = 768;
    bx = (t % 24) * 32; by = (t / 24) * 32;
  }
  __shared__ float tile[32][33];
  const int tx = threadIdx.x & 31, ty = threadIdx.x >> 5;
#pragma unroll
  for (int j = 0; j < 32; j += 8)
    tile[ty + j][tx] = in[(size_t)(by + ty + j) * N + bx + tx];
  __syncthreads();
#pragma unroll
  for (int j = 0; j < 32; j += 8)
    out[(size_t)(bx + ty + j) * K + by + tx] = f2bf(tile[tx][ty + j]);
}

// ---------------- GEMM: C = A[MxK] @ B^T[NxK]^T (+ bias) ----------------
// [LOCKED: R9/R11-proven best by GRAPH total. BK=32 dbuf, one barrier/iter,
//  32 KB LDS, line-pair swizzle (0 conflicts).]
// 128x128 tile, 4 waves (2x2), wave = 64x64 = 4x4 mfma 16x16x32 subtiles.
// EPI: 0 = QKV scatter   2 = gelu->bf16   3 = BF16 split-K partial
template <int EPI>
__global__ __launch_bounds__(256) void gemm_bt(
    const u16* __restrict__ A, const u16* __restrict__ BT,
    const float* __restrict__ bias, int M, int N, int K, int kchunk,
    float* __restrict__ outf, u16* __restrict__ outb,
    u16* __restrict__ qo, u16* __restrict__ ko, u16* __restrict__ vto) {
  __shared__ __align__(16) u16 lsA[2 * 128 * 32];
  __shared__ __align__(16) u16 lsB[2 * 128 * 32];
  const int tid = threadIdx.x;
  const int w = tid >> 6, lane = tid & 63;
  const int wm = w & 1, wn = w >> 1;
  const int lrow = lane & 15, quad = lane >> 4;
  const int m0 = blockIdx.y * 128, n0 = blockIdx.x * 128;
  const int kbeg = blockIdx.z * kchunk;

  f32x4 acc[4][4];
#pragma unroll
  for (int i = 0; i < 4; ++i)
#pragma unroll
    for (int j = 0; j < 4; ++j) acc[i][j] = (f32x4){0.f, 0.f, 0.f, 0.f};

  // staging: thread covers 16 B at LDS byte tid*16 of each 4 KB half-tile
  const int off = tid * 16;
  const int line = tid >> 3;           // 128-B line (2 rows of 64 B)
  const int slotp = tid & 7;           // 16-B slot within line
  const int p = slotp ^ (line & 7);    // logical pos = (row&1)*4 + chunk
  const int srow = line * 2 + (p >> 2);
  const int scol = (p & 3) * 8;        // u16 col within BK=32

  const u16* ga0 = A + (size_t)(m0 + srow) * K + scol;
  const u16* gb0 = BT + (size_t)(n0 + srow) * K + scol;

  auto stage = [&](int k0, int buf) {
    char* da = (char*)(lsA + buf * 4096);
    char* db = (char*)(lsB + buf * 4096);
    GLDS16(ga0 + k0, da + off);
    GLDS16(ga0 + k0 + (size_t)64 * K, da + 4096 + off);
    GLDS16(gb0 + k0, db + off);
    GLDS16(gb0 + k0 + (size_t)64 * K, db + 4096 + off);
  };

  // fragment read: row = wbase + ms*16 + lrow, chunk = quad
  const int lline = lrow >> 1;
  const int lslot = (((lrow & 1) << 2) + quad) ^ ((lrow >> 1) & 7);
  const int rdoff = lslot * 8;

  const int niter = kchunk >> 5;
  stage(kbeg, 0);
  for (int t = 0; t < niter; ++t) {
    __syncthreads();  // drains buf[t] prefetch (covered by compute of t-1)
    if (t + 1 < niter) stage(kbeg + (t + 1) * 32, (t + 1) & 1);
    const u16* Ab = lsA + (t & 1) * 4096;
    const u16* Bb = lsB + (t & 1) * 4096;
    bf16x8 af[4], bfr[4];
#pragma unroll
    for (int ms = 0; ms < 4; ++ms)
      af[ms] = *(const bf16x8*)&Ab[(wm * 32 + ms * 8 + lline) * 64 + rdoff];
#pragma unroll
    for (int ns = 0; ns < 4; ++ns)
      bfr[ns] = *(const bf16x8*)&Bb[(wn * 32 + ns * 8 + lline) * 64 + rdoff];
#pragma unroll
    for (int ms = 0; ms < 4; ++ms)
#pragma unroll
      for (int ns = 0; ns < 4; ++ns)
        acc[ms][ns] = MFMA_BF16(af[ms], bfr[ns], acc[ms][ns]);
  }

  u16* const pb = (EPI == 3) ? outb + (size_t)blockIdx.z * PSTRIDE : outb;
#pragma unroll
  for (int ms = 0; ms < 4; ++ms) {
    const int rbase = m0 + wm * 64 + ms * 16 + quad * 4;
#pragma unroll
    for (int ns = 0; ns < 4; ++ns) {
      const int col = n0 + wn * 64 + ns * 16 + lrow;
      if constexpr (EPI == 3) {
#pragma unroll
        for (int r = 0; r < 4; ++r)
          pb[(size_t)(rbase + r) * N + col] = f2bf(acc[ms][ns][r]);
      } else if constexpr (EPI == 2) {
        const float bcol = bias[col];
#pragma unroll
        for (int r = 0; r < 4; ++r) {
          float v = acc[ms][ns][r] + bcol;
          float g = 0.5f * v * (1.0f + erff(v * 0.7071067811865476f));
          outb[(size_t)(rbase + r) * N + col] = f2bf(g);
        }
      } else {  // QKV scatter
        const float bcol = bias[col];
        const int which = col / 768;
        const int rem = col - which * 768;
        const int hh = rem >> 6, dd = rem & 63;
        const int bI = rbase >> 11, sI = rbase & 2047;
        const size_t bh = (size_t)bI * 12 + hh;
        if (which == 0) {
#pragma unroll
          for (int r = 0; r < 4; ++r)
            qo[(bh * 2048 + sI + r) * 64 + dd] = f2bf((acc[ms][ns][r] + bcol) * QSCALE);
        } else if (which == 1) {
#pragma unroll
          for (int r = 0; r < 4; ++r)
            ko[(bh * 2048 + sI + r) * 64 + dd] = f2bf(acc[ms][ns][r] + bcol);
        } else {
          ushort4 pk;
          pk.x = f2bf(acc[ms][ns][0] + bcol);
          pk.y = f2bf(acc[ms][ns][1] + bcol);
          pk.z = f2bf(acc[ms][ns][2] + bcol);
          pk.w = f2bf(acc[ms][ns][3] + bcol);
          *(ushort4*)(vto + (bh * 64 + dd) * 2048 + sI) = pk;
        }
      }
    }
  }
}

// ---------------- flash attention (Q=128/block, split-KV z=2, dbuf K/V) -------------
// XCD-CLUSTERED grid: x = bh + 24*z (48 values, 48 % 8 == 0), y = q-tile (16).
// All 16 q-tile blocks sharing one (bh,z) K/V stream have linear ids spaced 48
// apart -> same XCD under round-robin dispatch -> K/V stays L2-resident
// (6 streams x 256 KB = 1.5 MB per XCD). [R15: 2.7x K/V over-fetch when the
// same blocks were id-adjacent and scattered across all 8 XCDs.]
// 4 waves; each wave owns 32 q rows (2 m-subtiles). Softmax-lite.
// Unnormalized bf16 partial O + fp32 denoms; attn_combine_k merges 2 partials.
__global__ __launch_bounds__(256) void attn_kernel(
    const u16* __restrict__ q, const u16* __restrict__ k,
    const u16* __restrict__ vT, u16* __restrict__ opart,
    float* __restrict__ lpart) {
  __shared__ __align__(16) u16 lsK[2 * 64 * 64];  // [buf][s][d], swizzled
  __shared__ __align__(16) u16 lsV[2 * 64 * 64];  // [buf][d][s], swizzled
  __shared__ __align__(16) u16 lsP[4][32 * 64];   // per-wave [m 0..31][j], swizzled
  const int tid = threadIdx.x;
  const int w = tid >> 6, lane = tid & 63;
  const int lrow = lane & 15, quad = lane >> 4;
  const int bhz = blockIdx.x;          // bh + 24*z
  const int bh = bhz % 24, z = bhz / 24;
  const int b = bh / 12, h = bh - b * 12;
  const int q0 = blockIdx.y * 128;
  const int kvbeg = z * (2048 / KVSPLIT);

  const u16* qbase = q + (size_t)bh * 2048 * 64;
  const u16* kbase = k + (size_t)bh * 2048 * 64;
  const u16* vbase = vT + (size_t)bh * 64 * 2048;

  bf16x8 qf[2][2];
#pragma unroll
  for (int m = 0; m < 2; ++m) {
    const int qrow = q0 + w * 32 + m * 16 + lrow;
    qf[m][0] = *(const bf16x8*)(qbase + (size_t)qrow * 64 + quad * 8);
    qf[m][1] = *(const bf16x8*)(qbase + (size_t)qrow * 64 + 32 + quad * 8);
  }

  float lsum[2][4] = {{0.f, 0.f, 0.f, 0.f}, {0.f, 0.f, 0.f, 0.f}};
  f32x4 oacc[2][4];
#pragma unroll
  for (int m = 0; m < 2; ++m)
#pragma unroll
    for (int d = 0; d < 4; ++d) oacc[m][d] = (f32x4){0.f, 0.f, 0.f, 0.f};

  const int off = tid * 16;
  const int srow = off >> 7;
  const int schunk = (off >> 4) & 7;
  const int sxc = schunk ^ (srow & 7);
  const int ksrc = srow * 64 + sxc * 8;
  const int vsrc0 = srow * 2048 + sxc * 8;

  const int c0 = quad ^ (lrow & 7);
  const int rd0 = c0 * 8, rd1 = (c0 ^ 4) * 8;

  u16* const lsPw = &lsP[w][0];
  const int jhi_base = lrow >> 3, jlo = lrow & 7;

  auto stage = [&](int kt, int buf) {
    char* dk = (char*)(lsK + buf * 4096);
    char* dv = (char*)(lsV + buf * 4096);
    GLDS16(kbase + (size_t)kt * 64 + ksrc, dk + off);
    GLDS16(kbase + (size_t)(kt + 32) * 64 + ksrc, dk + 4096 + off);
    GLDS16(vbase + vsrc0 + kt, dv + off);
    GLDS16(vbase + vsrc0 + kt + 32 * 2048, dv + 4096 + off);
  };

  const int ntiles = 2048 / KVSPLIT / 64;  // 16
  stage(kvbeg, 0);
  for (int t = 0; t < ntiles; ++t) {
    __syncthreads();
    if (t + 1 < ntiles) stage(kvbeg + (t + 1) * 64, (t + 1) & 1);
    const u16* Kb = lsK + (t & 1) * 4096;
    const u16* Vb = lsV + (t & 1) * 4096;

    f32x4 sc[2][4];
#pragma unroll
    for (int ns = 0; ns < 4; ++ns) {
      const u16* kr = Kb + (ns * 16 + lrow) * 64;
      bf16x8 kf0 = *(const bf16x8*)(kr + rd0);
      bf16x8 kf1 = *(const bf16x8*)(kr + rd1);
#pragma unroll
      for (int m = 0; m < 2; ++m) {
        sc[m][ns] = (f32x4){0.f, 0.f, 0.f, 0.f};
        sc[m][ns] = MFMA_BF16(qf[m][0], kf0, sc[m][ns]);
        sc[m][ns] = MFMA_BF16(qf[m][1], kf1, sc[m][ns]);
      }
    }

#pragma unroll
    for (int m = 0; m < 2; ++m)
#pragma unroll
      for (int ns = 0; ns < 4; ++ns) {
        const int jhi = ns * 2 + jhi_base;
#pragma unroll
        for (int r = 0; r < 4; ++r) {
          float p = __builtin_amdgcn_exp2f(sc[m][ns][r]);
          lsum[m][r] += p;
          union { float f; unsigned u; } cv; cv.f = p;
          const int row7 = (quad * 4 + r) & 7;
          lsPw[(m * 16 + quad * 4 + r) * 64 + ((jhi ^ row7) * 8) + jlo] =
              (u16)(cv.u >> 16);
        }
      }

    // PV (wave-private P: same-wave DS ordering, no barrier needed)
#pragma unroll
    for (int d = 0; d < 4; ++d) {
      const u16* vr = Vb + (d * 16 + lrow) * 64;
      bf16x8 vf0 = *(const bf16x8*)(vr + rd0);
      bf16x8 vf1 = *(const bf16x8*)(vr + rd1);
#pragma unroll
      for (int m = 0; m < 2; ++m) {
        const u16* pr = lsPw + (m * 16 + lrow) * 64;
        bf16x8 pf0 = *(const bf16x8*)(pr + rd0);
        bf16x8 pf1 = *(const bf16x8*)(pr + rd1);
        oacc[m][d] = MFMA_BF16(pf0, vf0, oacc[m][d]);
        oacc[m][d] = MFMA_BF16(pf1, vf1, oacc[m][d]);
      }
    }
  }

#pragma unroll
  for (int m = 0; m < 2; ++m)
#pragma unroll
    for (int r = 0; r < 4; ++r) {
#pragma unroll
      for (int mm = 1; mm <= 8; mm <<= 1)
        lsum[m][r] += __shfl_xor(lsum[m][r], mm);
    }

  u16* const op = opart + (size_t)z * PSTRIDE;
#pragma unroll
  for (int m = 0; m < 2; ++m) {
    const int srow_out = q0 + w * 32 + m * 16 + quad * 4;
#pragma unroll
    for (int d = 0; d < 4; ++d)
#pragma unroll
      for (int r = 0; r < 4; ++r)
        op[(size_t)(b * 2048 + srow_out + r) * 768 + h * 64 + d * 16 + lrow] =
            f2bf(oacc[m][d][r]);
    if (lrow == 0) {
#pragma unroll
      for (int r = 0; r < 4; ++r)
        lpart[(size_t)(z * 24 + bh) * 2048 + srow_out + r] = lsum[m][r];
    }
  }
}

// ctx = (sum_z o_z) / (sum_z l_z), bf16; vectorized x4
__global__ __launch_bounds__(256) void attn_combine_k(
    const u16* __restrict__ op, const float* __restrict__ lp,
    u16* __restrict__ ctx) {
  const unsigned idx = (blockIdx.x * 256u + threadIdx.x) * 4u;
  const unsigned row = idx / 768u;
  const unsigned c = idx - row * 768u;
  const int b = row >> 11, s = row & 2047;
  const int h = c >> 6;
  const size_t li = (size_t)(b * 12 + h) * 2048 + s;
  float l = 0.f;
  float sx = 0.f, sy = 0.f, sz = 0.f, sw = 0.f;
#pragma unroll
  for (int p = 0; p < KVSPLIT; ++p) {
    l += lp[(size_t)p * 24 * 2048 + li];
    ushort4 o = *(const ushort4*)(op + (size_t)p * PSTRIDE + idx);
    sx += bf2f(o.x); sy += bf2f(o.y); sz += bf2f(o.z); sw += bf2f(o.w);
  }
  const float rinv = 1.f / l;
  ushort4 out;
  out.x = f2bf(sx * rinv); out.y = f2bf(sy * rinv);
  out.z = f2bf(sz * rinv); out.w = f2bf(sw * rinv);
  *(ushort4*)(ctx + idx) = out;
}

// ---------------- bf16-partial-sum + bias + residual + layernorm ----------------
__global__ __launch_bounds__(256) void ln_kernel(
    const u16* __restrict__ parts, int nparts, const float* __restrict__ bias,
    const float* __restrict__ res, const float* __restrict__ g,
    const float* __restrict__ bb, float* __restrict__ outf, u16* __restrict__ outb) {
  const int row = blockIdx.x;
  const int tid = threadIdx.x;
  const float* pr = res + (size_t)row * 768;
  float v[3], s = 0.f, s2 = 0.f;
#pragma unroll
  for (int j = 0; j < 3; ++j) {
    const int c = tid + j * 256;
    float t = bias[c] + pr[c];
    for (int p = 0; p < nparts; ++p)
      t += bf2f(parts[p * PSTRIDE + (size_t)row * 768 + c]);
    v[j] = t; s += t; s2 += t * t;
  }
#pragma unroll
  for (int m = 32; m > 0; m >>= 1) {
    s += __shfl_xor(s, m);
    s2 += __shfl_xor(s2, m);
  }
  __shared__ float red[8];
  const int w = tid >> 6, lane = tid & 63;
  if (lane == 0) { red[w] = s; red[4 + w] = s2; }
  __syncthreads();
  s = red[0] + red[1] + red[2] + red[3];
  s2 = red[4] + red[5] + red[6] + red[7];
  const float mu = s * (1.f / 768.f);
  const float var = s2 * (1.f / 768.f) - mu * mu;
  const float rstd = rsqrtf(var + 1e-5f);
#pragma unroll
  for (int j = 0; j < 3; ++j) {
    const int c = tid + j * 256;
    const float y = (v[j] - mu) * rstd * g[c] + bb[c];
    if (outf) outf[(size_t)row * 768 + c] = y;
    if (outb) outb[(size_t)row * 768 + c] = f2bf(y);
  }
}

// ---------------- launch ----------------
extern "C" void kernel_launch(void* const* d_in, const int* in_sizes, int n_in,
                              void* d_out, int out_size, void* d_ws, size_t ws_size,
                              hipStream_t stream) {
  const float* x    = (const float*)d_in[0];
  const float* Wq   = (const float*)d_in[1];
  const float* bq   = (const float*)d_in[2];
  const float* Wk   = (const float*)d_in[3];
  const float* bk   = (const float*)d_in[4];
  const float* Wv   = (const float*)d_in[5];
  const float* bv   = (const float*)d_in[6];
  const float* Wo   = (const float*)d_in[7];
  const float* bo   = (const float*)d_in[8];
  const float* W1   = (const float*)d_in[9];
  const float* b1   = (const float*)d_in[10];
  const float* W2   = (const float*)d_in[11];
  const float* b2   = (const float*)d_in[12];
  const float* ln1g = (const float*)d_in[13];
  const float* ln1b = (const float*)d_in[14];
  const float* ln2g = (const float*)d_in[15];
  const float* ln2b = (const float*)d_in[16];

  char* ws = (char*)d_ws;
  size_t off = 0;
  auto alloc = [&](size_t bytes) {
    void* p = ws + off;
    off += (bytes + 255) & ~(size_t)255;
    return p;
  };
  // persistent weights (14.2 MB)
  u16*  WqkvT = (u16*)alloc(2304ull * 768 * 2);
  u16*  WoT   = (u16*)alloc(768ull * 768 * 2);
  u16*  W1T   = (u16*)alloc(3072ull * 768 * 2);
  u16*  W2T   = (u16*)alloc(768ull * 3072 * 2);
  float* bqkv = (float*)alloc(2304 * 4);
  // bigbase region: [xb qb kb vtb] (25.2 MB). Aliased later by:
  //   wop  (Wo bf16 partials z=2, 12.6 MB)  — xb..vtb dead after combine
  //   f2bp (FFN2 bf16 partials z=4, 25.2 MB) — wop dead after ln1
  char* bigbase = (char*)alloc(0);
  u16*  xb    = (u16*)alloc(4096ull * 768 * 2);
  u16*  qb    = (u16*)alloc(24ull * 2048 * 64 * 2);
  u16*  kb    = (u16*)alloc(24ull * 2048 * 64 * 2);
  u16*  vtb   = (u16*)alloc(24ull * 64 * 2048 * 2);
  u16*  ctx   = (u16*)alloc(4096ull * 768 * 2);
  float* lpart = (float*)alloc((size_t)KVSPLIT * 24 * 2048 * 4);
  // tail (contiguous): hbuf | hb | f1
  float* hbuf  = (float*)alloc(4096ull * 768 * 4);
  u16*  hb    = (u16*)alloc(4096ull * 768 * 2);
  u16*  f1    = (u16*)alloc(4096ull * 3072 * 2);
  // aliases (no fresh allocation; layout hardware-validated in R14):
  u16*  wop   = (u16*)bigbase;      // dead xb..vtb after attention combine
  u16*  f2bp  = (u16*)bigbase;      // dead wop after ln1
  u16*  opart = (u16*)hbuf;         // attn partials (z=2: 12.6 MB, exactly over hbuf),
                                    // dead during attention; consumed before ln1 writes hbuf

  // one fused prep launch: 6 transposes + bias concat + x convert
  prep_weights_k<<<9993, 256, 0, stream>>>(Wq, Wk, Wv, Wo, W1, W2, bq, bk, bv, x,
                                           WqkvT, WoT, W1T, W2T, bqkv, xb);

  // QKV: M=4096 N=2304 K=768
  gemm_bt<0><<<dim3(18, 32, 1), 256, 0, stream>>>(xb, WqkvT, bqkv, 4096, 2304, 768, 768,
                                                  nullptr, nullptr, qb, kb, vtb);
  // attention: XCD-clustered grid (bh+24z in x, q-tile in y), split-KV z=2
  attn_kernel<<<dim3(24 * KVSPLIT, 16, 1), 256, 0, stream>>>(qb, kb, vtb, opart, lpart);
  attn_combine_k<<<3072, 256, 0, stream>>>(opart, lpart, ctx);
  // Wo: split-K z=2 -> 2 bf16 partials in wop (over dead xb/qb)
  gemm_bt<3><<<dim3(6, 32, 2), 256, 0, stream>>>(ctx, WoT, nullptr, 4096, 768, 768, 384,
                                                 nullptr, wop, nullptr, nullptr, nullptr);
  ln_kernel<<<4096, 256, 0, stream>>>(wop, 2, bo, x, ln1g, ln1b, hbuf, hb);
  // FFN1: M=4096 N=3072 K=768, GELU epilogue
  gemm_bt<2><<<dim3(24, 32, 1), 256, 0, stream>>>(hb, W1T, b1, 4096, 3072, 768, 768,
                                                  nullptr, f1, nullptr, nullptr, nullptr);
  // FFN2: split-K z=4 -> 4 bf16 partials in f2bp (over dead wop/bigbase)
  gemm_bt<3><<<dim3(6, 32, 4), 256, 0, stream>>>(f1, W2T, nullptr, 4096, 768, 3072, 768,
                                                 nullptr, f2bp, nullptr, nullptr, nullptr);
  ln_kernel<<<4096, 256, 0, stream>>>(f2bp, 4, b2, hbuf, ln2g, ln2b, (float*)d_out, nullptr);
}